// Round 16
// baseline (515.478 us; speedup 1.0000x reference)
//
#include <hip/hip_runtime.h>
#include <hip/hip_bf16.h>

// SelfAttention: out = softmax(causal((Ez Wq^T)(Ez Wk^T)^T / sqrt(512))) (Ez Wv^T)
// B=32, L=2048, DIM=512. f32 in/out; bf16 MFMA internally.
// ws: Qb (bf16, Q*SCALE*LOG2E), Kb (bf16), Vtb (bf16, [b][t][e][32] tile-contig,
// chunk-XOR pre-baked). Wb (bf16 [g][kt][n][32], swizzled) in d_out scratch.
// R16 = R15 + d-split PV: wave w computes out dims [w*64,+64) for ALL 128 rows;
// P/alpha DOUBLE-BUFFERED in LDS by t&1 (fixes the R10/R11 race); V LDS reads
// per wave 32KB -> 4KB. Lagged PV (R15) keeps one barrier per tile.

typedef __attribute__((ext_vector_type(8))) short short8;
typedef __attribute__((ext_vector_type(4))) short short4v;
typedef __attribute__((ext_vector_type(4))) float f32x4;

#define DIM 512
#define LSEQ 2048
#define NB 32
#define SCALE 0.04419417382415922f
#define LOG2E 1.4426950408889634f

__device__ __forceinline__ short f2bs(float f) {
  __hip_bfloat16 h = __float2bfloat16(f);
  return __builtin_bit_cast(short, h);
}

__device__ __forceinline__ void gld16(const void* g, void* l) {
  __builtin_amdgcn_global_load_lds(
      (const unsigned int __attribute__((address_space(1)))*)g,
      (unsigned int __attribute__((address_space(3)))*)l, 16, 0, 0);
}

// ---- W[z] f32 -> bf16, layout [g][kt][n][32 d-chunk-swizzled] --------------
__global__ __launch_bounds__(256) void wcvt_kernel(
    const float* __restrict__ Wq, const float* __restrict__ Wk,
    const float* __restrict__ Wv, const int* __restrict__ zp,
    short* __restrict__ Wb) {
  int z = *zp;
  int i = blockIdx.x * 256 + threadIdx.x;
  int g = i >> 15;
  int off = (i & 32767) * 8;                   // flat [n][d], d fast
  int n = off >> 9, d0 = off & 511;
  int kt = d0 >> 5, c = d0 & 31;
  int sw = ((c >> 3) ^ ((n >> 1) & 3));
  const float* src = (g == 0 ? Wq : (g == 1 ? Wk : Wv)) + (size_t)z * DIM * DIM + off;
  float4 a = *(const float4*)src, b = *(const float4*)(src + 4);
  short8 v;
  v[0]=f2bs(a.x); v[1]=f2bs(a.y); v[2]=f2bs(a.z); v[3]=f2bs(a.w);
  v[4]=f2bs(b.x); v[5]=f2bs(b.y); v[6]=f2bs(b.z); v[7]=f2bs(b.w);
  *(short8*)&Wb[((size_t)(g * 16 + kt) * 512 + n) * 32 + sw * 8] = v;
}

// ---- projection GEMM: C[m][n] = sum_d Ez[m][d] * W[n][d] -------------------
__global__ __launch_bounds__(512, 4) void proj_kernel(
    const float* __restrict__ Ez, const short* __restrict__ Wb,
    short* __restrict__ Qb, short* __restrict__ Kb, short* __restrict__ Vtb) {
  int g = blockIdx.z;
  const short* W = Wb + (size_t)g * 16 * 512 * 32;
  __shared__ short As[2][64 * 32];
  __shared__ short Bs[2][512 * 32];
  int tid = threadIdx.x, lane = tid & 63, wid = tid >> 6;
  int l15 = lane & 15, lg = lane >> 4;
  int m0 = blockIdx.x * 64;
  int sw = (l15 >> 1) & 3;
  f32x4 zero4 = {0.f, 0.f, 0.f, 0.f};
  f32x4 acc[4][4];
  #pragma unroll
  for (int mi = 0; mi < 4; mi++)
    #pragma unroll
    for (int ni = 0; ni < 4; ni++) acc[mi][ni] = zero4;

  int arow = tid >> 3, aq = tid & 7;
  int aoff = arow * 32 + (((aq >> 1) ^ ((arow >> 1) & 3)) << 3) + (aq & 1) * 4;
  const float* aptr = Ez + (size_t)(m0 + arow) * DIM + aq * 4;

  {  // prologue: stage kt=0
    float4 a = *(const float4*)aptr;
    short4v av;
    av[0]=f2bs(a.x); av[1]=f2bs(a.y); av[2]=f2bs(a.z); av[3]=f2bs(a.w);
    *(short4v*)&As[0][aoff] = av;
    #pragma unroll
    for (int ii = 0; ii < 4; ii++) {
      int s = wid * 4 + ii;
      gld16(W + s * 512 + lane * 8, &Bs[0][s * 512]);
    }
  }
  __syncthreads();

  #pragma unroll 2
  for (int kt = 0; kt < 16; kt++) {
    int cur = kt & 1;
    float4 a;
    if (kt < 15) {
      a = *(const float4*)(aptr + (kt + 1) * 32);
      #pragma unroll
      for (int ii = 0; ii < 4; ii++) {
        int s = wid * 4 + ii;
        gld16(W + (size_t)(kt + 1) * 16384 + s * 512 + lane * 8, &Bs[cur ^ 1][s * 512]);
      }
    }
    short8 af[4], bf[4];
    #pragma unroll
    for (int mi = 0; mi < 4; mi++)
      af[mi] = *(const short8*)&As[cur][(mi * 16 + l15) * 32 + ((lg ^ sw) << 3)];
    #pragma unroll
    for (int ni = 0; ni < 4; ni++)
      bf[ni] = *(const short8*)&Bs[cur][(wid * 64 + ni * 16 + l15) * 32 + ((lg ^ sw) << 3)];
    __builtin_amdgcn_s_setprio(1);
    #pragma unroll
    for (int mi = 0; mi < 4; mi++)
      #pragma unroll
      for (int ni = 0; ni < 4; ni++)
        acc[mi][ni] = __builtin_amdgcn_mfma_f32_16x16x32_bf16(af[mi], bf[ni], acc[mi][ni], 0, 0, 0);
    __builtin_amdgcn_s_setprio(0);
    if (kt < 15) {
      short4v av;
      av[0]=f2bs(a.x); av[1]=f2bs(a.y); av[2]=f2bs(a.z); av[3]=f2bs(a.w);
      *(short4v*)&As[cur ^ 1][aoff] = av;
    }
    __syncthreads();
  }

  if (g == 2) {
    #pragma unroll
    for (int mi = 0; mi < 4; mi++) {
      int gm0 = m0 + mi * 16 + lg * 4;
      int b = gm0 >> 11, l0 = gm0 & (LSEQ - 1);
      int t = l0 >> 5, c0 = l0 & 31;
      #pragma unroll
      for (int ni = 0; ni < 4; ni++) {
        int e = wid * 64 + ni * 16 + l15;
        short4v v;
        v[0]=f2bs(acc[mi][ni][0]); v[1]=f2bs(acc[mi][ni][1]);
        v[2]=f2bs(acc[mi][ni][2]); v[3]=f2bs(acc[mi][ni][3]);
        size_t idx = ((size_t)(b * 64 + t) * 512 + e) * 32
                     + (((c0 >> 3) ^ ((e >> 1) & 3)) << 3) + (c0 & 7);
        *(short4v*)&Vtb[idx] = v;   // tile-contiguous V, read-swizzle pre-baked
      }
    }
  } else {
    short* dst = (g == 0 ? Qb : Kb);
    float sc = (g == 0 ? SCALE * LOG2E : 1.0f);  // Q pre-scaled, exp2 domain
    #pragma unroll
    for (int mi = 0; mi < 4; mi++) {
      int gm0 = m0 + mi * 16 + lg * 4;
      #pragma unroll
      for (int ni = 0; ni < 4; ni++) {
        int gn = wid * 64 + ni * 16 + l15;
        #pragma unroll
        for (int r = 0; r < 4; r++)
          dst[(size_t)(gm0 + r) * DIM + gn] = f2bs(acc[mi][ni][r] * sc);
      }
    }
  }
}

// ---- flash attention (causal) ----------------------------------------------
__device__ __forceinline__ void stage_k(const short* __restrict__ Kb,
                                        short* Klbuf,
                                        int batch, int t, int wid, int lane) {
  #pragma unroll
  for (int ii = 0; ii < 4; ii++) {          // K: rows wid, wid+8, wid+16, wid+24
    int r = wid + ii * 8;                   // r&7 == wid
    const short* src = Kb + (size_t)(batch * LSEQ + t * 32 + r) * DIM + ((lane ^ wid) * 8);
    gld16(src, Klbuf + r * 512);
  }
}
__device__ __forceinline__ void stage_v(const short* __restrict__ Vtb,
                                        short* Vlbuf,
                                        int batch, int t, int wid, int lane) {
  const short* vt = Vtb + (size_t)(batch * 64 + t) * 16384;  // contiguous 32KB
  #pragma unroll
  for (int ii = 0; ii < 4; ii++) {
    int s = wid * 4 + ii;
    gld16(vt + s * 512 + lane * 8, Vlbuf + s * 512);
  }
}

__global__ __launch_bounds__(512, 2) void attn_kernel(
    const short* __restrict__ Qb, const short* __restrict__ Kb,
    const short* __restrict__ Vtb, float* __restrict__ out) {
  __shared__ short Kl[2][32 * 512];      // 64 KB dbuf
  __shared__ short Vl[2][512 * 32];      // 64 KB dbuf
  __shared__ short P_lds[2][8][16][40];  // P double-buffered by t&1; 20.5 KB
  __shared__ float alpha_lds[2][8];
  __shared__ float dsum[128];
  int tid = threadIdx.x, lane = tid & 63, wid = tid >> 6;
  int l15 = lane & 15, lg = lane >> 4;
  int batch = blockIdx.x;
  f32x4 zero4 = {0.f, 0.f, 0.f, 0.f};
  short8 ones;
  #pragma unroll
  for (int i = 0; i < 8; i++) ones[i] = (short)0x3F80;

  // lane-const LDS offsets (shorts):
  int a0 = (l15 >> 2) & 1, b0 = l15 & 3;
  int kqE = l15 * 512 + 8 * (lg ^ b0) + 32 * a0;  // even-kt base (+8192 for c=1)
  int kqO = l15 * 512 + 8 * (lg ^ b0) - 32 * a0;  // odd-kt base
  int voff = wid * 2048 + l15 * 32 + 8 * (lg ^ ((l15 >> 1) & 3));  // own 64-dim V slice
  short* pw = &P_lds[0][wid][lg * 4][l15];        // write: +pb*5120 +40*r (+16)
  const short* prd = &P_lds[0][0][l15][lg * 8];   // read:  +pb*5120 +640*qt8

  for (int qpass = 0; qpass < 2; qpass++) {
    int qt = qpass ? (int)blockIdx.y : 15 - (int)blockIdx.y;  // long pass first
    int qb0 = qt * 128;
    int q0w = qb0 + wid * 16;
    int nt = qt * 4 + 4;

    stage_k(Kb, Kl[0], batch, 0, wid, lane);  // prologue: K(0)

    const short* qrow = Qb + (size_t)(batch * LSEQ + q0w + l15) * DIM;
    short8 qf[16];  // Q rows in regs (SCALE*LOG2E pre-folded)
    #pragma unroll
    for (int kt = 0; kt < 16; kt++) qf[kt] = *(const short8*)(qrow + kt * 32 + lg * 8);

    f32x4 oacc[8][4];  // [q-tile][e4]: all 128 rows x dims [wid*64,+64)
    #pragma unroll
    for (int i = 0; i < 8; i++)
      #pragma unroll
      for (int j = 0; j < 4; j++) oacc[i][j] = zero4;
    f32x4 dacc = zero4;   // own q-tile denominator
    float mrun = -1e30f;

    __syncthreads();  // drains prologue stage (vmcnt) + syncs

    for (int t = 0; t < nt; t++) {
      int cur = t & 1, pb = cur ^ 1;  // pb = (t-1)&1
      if (t + 1 < nt)
        stage_k(Kb, Kl[cur ^ 1], batch, t + 1, wid, lane);
      stage_v(Vtb, Vl[cur], batch, t, wid, lane);  // V(t): consumed iter t+1

      bool act = (t * 32 <= q0w + 15);
      f32x4 sacc[2] = {zero4, zero4};

      if (t > 0) {
        bool pvact[8];
        float af8[8];
        #pragma unroll
        for (int j = 0; j < 8; j++) {
          pvact[j] = ((t - 1) * 32 <= qb0 + j * 16 + 15);
          af8[j] = alpha_lds[pb][j];
        }
        const short* vb = Vl[pb] + voff;  // V(t-1) in buffer (t-1)&1 == pb
        const short* pbase = prd + pb * 5120;
        __builtin_amdgcn_s_setprio(1);
        if (pvact[wid]) {  // dacc += own P(t-1) row-sums
          short8 paw = *(const short8*)(pbase + wid * 640);
          dacc = __builtin_amdgcn_mfma_f32_16x16x32_bf16(paw, ones, dacc, 0, 0, 0);
        }
        if (act) {  // zip: QK(t) interleaved with PV(t-1)
          const short* pE = Kl[cur] + kqE;
          const short* pO = Kl[cur] + kqO;
          #pragma unroll
          for (int j = 0; j < 8; j++) {
            int kt = 2 * j;
            short8 k0 = *(const short8*)(pE + 32 * kt);
            short8 k1 = *(const short8*)(pE + 8192 + 32 * kt);
            sacc[0] = __builtin_amdgcn_mfma_f32_16x16x32_bf16(qf[kt], k0, sacc[0], 0, 0, 0);
            sacc[1] = __builtin_amdgcn_mfma_f32_16x16x32_bf16(qf[kt], k1, sacc[1], 0, 0, 0);
            if (pvact[j]) {
              short8 pA = *(const short8*)(pbase + j * 640);
              float a = af8[j];
              if (a != 1.0f) {
                #pragma unroll
                for (int e4 = 0; e4 < 4; e4++) {
                  oacc[j][e4][0] *= a; oacc[j][e4][1] *= a;
                  oacc[j][e4][2] *= a; oacc[j][e4][3] *= a;
                }
              }
              #pragma unroll
              for (int e4 = 0; e4 < 4; e4++) {
                short8 bv = *(const short8*)(vb + e4 * 512);
                oacc[j][e4] = __builtin_amdgcn_mfma_f32_16x16x32_bf16(pA, bv, oacc[j][e4], 0, 0, 0);
              }
            }
            short8 k2 = *(const short8*)(pO + 32 * (kt + 1));
            short8 k3 = *(const short8*)(pO + 8192 + 32 * (kt + 1));
            sacc[0] = __builtin_amdgcn_mfma_f32_16x16x32_bf16(qf[kt + 1], k2, sacc[0], 0, 0, 0);
            sacc[1] = __builtin_amdgcn_mfma_f32_16x16x32_bf16(qf[kt + 1], k3, sacc[1], 0, 0, 0);
          }
        } else {  // PV(t-1) only
          #pragma unroll
          for (int j = 0; j < 8; j++) {
            if (pvact[j]) {
              short8 pA = *(const short8*)(pbase + j * 640);
              float a = af8[j];
              if (a != 1.0f) {
                #pragma unroll
                for (int e4 = 0; e4 < 4; e4++) {
                  oacc[j][e4][0] *= a; oacc[j][e4][1] *= a;
                  oacc[j][e4][2] *= a; oacc[j][e4][3] *= a;
                }
              }
              #pragma unroll
              for (int e4 = 0; e4 < 4; e4++) {
                short8 bv = *(const short8*)(vb + e4 * 512);
                oacc[j][e4] = __builtin_amdgcn_mfma_f32_16x16x32_bf16(pA, bv, oacc[j][e4], 0, 0, 0);
              }
            }
          }
        }
        __builtin_amdgcn_s_setprio(0);
      } else if (act) {  // t == 0: QK only
        const short* pE = Kl[cur] + kqE;
        const short* pO = Kl[cur] + kqO;
        __builtin_amdgcn_s_setprio(1);
        #pragma unroll
        for (int kt = 0; kt < 16; kt += 2) {
          short8 k0 = *(const short8*)(pE + 32 * kt);
          short8 k1 = *(const short8*)(pE + 8192 + 32 * kt);
          sacc[0] = __builtin_amdgcn_mfma_f32_16x16x32_bf16(qf[kt], k0, sacc[0], 0, 0, 0);
          sacc[1] = __builtin_amdgcn_mfma_f32_16x16x32_bf16(qf[kt], k1, sacc[1], 0, 0, 0);
          short8 k2 = *(const short8*)(pO + 32 * (kt + 1));
          short8 k3 = *(const short8*)(pO + 8192 + 32 * (kt + 1));
          sacc[0] = __builtin_amdgcn_mfma_f32_16x16x32_bf16(qf[kt + 1], k2, sacc[0], 0, 0, 0);
          sacc[1] = __builtin_amdgcn_mfma_f32_16x16x32_bf16(qf[kt + 1], k3, sacc[1], 0, 0, 0);
        }
        __builtin_amdgcn_s_setprio(0);
      }

      if (act) {  // softmax(t): mask, lazy max (rescales dacc only), publish P
        if (t * 32 + 31 > q0w) {
          #pragma unroll
          for (int r = 0; r < 4; r++) {
            int q = q0w + lg * 4 + r;
            if (t * 32 + l15 > q) sacc[0][r] = -1e30f;
            if (t * 32 + 16 + l15 > q) sacc[1][r] = -1e30f;
          }
        }
        float lm = fmaxf(
            fmaxf(fmaxf(sacc[0][0], sacc[0][1]), fmaxf(sacc[0][2], sacc[0][3])),
            fmaxf(fmaxf(sacc[1][0], sacc[1][1]), fmaxf(sacc[1][2], sacc[1][3])));
        float alpha_t = 1.0f;
        if (__any(lm > mrun + 11.5f)) {
          float mx = lm;
          #pragma unroll
          for (int off = 1; off < 64; off <<= 1) mx = fmaxf(mx, __shfl_xor(mx, off, 64));
          alpha_t = exp2f(mrun - mx);
          mrun = mx;
          dacc[0] *= alpha_t; dacc[1] *= alpha_t;
          dacc[2] *= alpha_t; dacc[3] *= alpha_t;
        }
        int pboff = cur * 5120;
        #pragma unroll
        for (int r = 0; r < 4; r++) {
          pw[pboff + r * 40] = f2bs(exp2f(sacc[0][r] - mrun));
          pw[pboff + r * 40 + 16] = f2bs(exp2f(sacc[1][r] - mrun));
        }
        if (lane == 0) alpha_lds[cur][wid] = alpha_t;
      }
      __syncthreads();  // P(t)/alpha(t) visible; vmcnt drained; buffers released
    }

    {  // drain: PV(nt-1), buffers (nt-1)&1
      int pb = (nt - 1) & 1;
      const short* vb = Vl[pb] + voff;
      const short* pbase = prd + pb * 5120;
      if ((nt - 1) * 32 <= q0w + 15) {
        short8 paw = *(const short8*)(pbase + wid * 640);
        dacc = __builtin_amdgcn_mfma_f32_16x16x32_bf16(paw, ones, dacc, 0, 0, 0);
      }
      #pragma unroll
      for (int j = 0; j < 8; j++) {
        if ((nt - 1) * 32 <= qb0 + j * 16 + 15) {
          short8 pA = *(const short8*)(pbase + j * 640);
          float a = alpha_lds[pb][j];
          if (a != 1.0f) {
            #pragma unroll
            for (int e4 = 0; e4 < 4; e4++) {
              oacc[j][e4][0] *= a; oacc[j][e4][1] *= a;
              oacc[j][e4][2] *= a; oacc[j][e4][3] *= a;
            }
          }
          #pragma unroll
          for (int e4 = 0; e4 < 4; e4++) {
            short8 bv = *(const short8*)(vb + e4 * 512);
            oacc[j][e4] = __builtin_amdgcn_mfma_f32_16x16x32_bf16(pA, bv, oacc[j][e4], 0, 0, 0);
          }
        }
      }
    }
    // epilogue: broadcast denominators, write all q-tiles x own dim slice
    if (l15 == 0) {
      #pragma unroll
      for (int r = 0; r < 4; r++) dsum[wid * 16 + lg * 4 + r] = dacc[r];
    }
    __syncthreads();
    #pragma unroll
    for (int j = 0; j < 8; j++)
      #pragma unroll
      for (int r = 0; r < 4; r++) {
        float inv = 1.0f / dsum[j * 16 + lg * 4 + r];
        int q = qb0 + j * 16 + lg * 4 + r;
        #pragma unroll
        for (int e4 = 0; e4 < 4; e4++)
          out[((size_t)(batch * LSEQ + q)) * DIM + wid * 64 + e4 * 16 + l15] =
              oacc[j][e4][r] * inv;
      }
    __syncthreads();  // LDS reuse safe before next qpass
  }
}

extern "C" void kernel_launch(void* const* d_in, const int* in_sizes, int n_in,
                              void* d_out, int out_size, void* d_ws, size_t ws_size,
                              hipStream_t stream) {
  const float* Ez = (const float*)d_in[0];
  const float* Wq = (const float*)d_in[1];
  const float* Wk = (const float*)d_in[2];
  const float* Wv = (const float*)d_in[3];
  const int* zp = (const int*)d_in[4];
  float* out = (float*)d_out;
  short* Qb = (short*)d_ws;
  short* Kb = Qb + (size_t)NB * LSEQ * DIM;
  short* Vtb = Kb + (size_t)NB * LSEQ * DIM;
  short* Wb = (short*)d_out;  // scratch: proj completes before attn writes out
  hipLaunchKernelGGL(wcvt_kernel, dim3(384), dim3(256), 0, stream,
                     Wq, Wk, Wv, zp, Wb);
  hipLaunchKernelGGL(proj_kernel, dim3(1024, 1, 3), dim3(512), 0, stream,
                     Ez, Wb, Qb, Kb, Vtb);
  hipLaunchKernelGGL(attn_kernel, dim3(32, 8), dim3(512), 0, stream,
                     Qb, Kb, Vtb, out);
}

// Round 17
// 498.094 us; speedup vs baseline: 1.0349x; 1.0349x over previous
//
#include <hip/hip_runtime.h>
#include <hip/hip_bf16.h>

// SelfAttention: out = softmax(causal((Ez Wq^T)(Ez Wk^T)^T / sqrt(512))) (Ez Wv^T)
// B=32, L=2048, DIM=512. f32 in/out; bf16 MFMA internally.
// ws: Qb (bf16, Q*SCALE*LOG2E), Kb (bf16), Vtb (bf16, [b][t][e][32] tile-contig,
// chunk-XOR pre-baked). Wb (bf16 [g][kt][n][32], swizzled) in d_out scratch.
// R17 = R15 lagged pipeline + 2-way paired e-split PV: wave w computes q-rows
// of pair {w&~1, w|1} (32 rows) x dims [(w&1)*256,+256). P/alpha double-
// buffered by t&1 (R16-verified). V LDS reads per wave halve (32->16 KB).

typedef __attribute__((ext_vector_type(8))) short short8;
typedef __attribute__((ext_vector_type(4))) short short4v;
typedef __attribute__((ext_vector_type(4))) float f32x4;

#define DIM 512
#define LSEQ 2048
#define NB 32
#define SCALE 0.04419417382415922f
#define LOG2E 1.4426950408889634f

__device__ __forceinline__ short f2bs(float f) {
  __hip_bfloat16 h = __float2bfloat16(f);
  return __builtin_bit_cast(short, h);
}

__device__ __forceinline__ void gld16(const void* g, void* l) {
  __builtin_amdgcn_global_load_lds(
      (const unsigned int __attribute__((address_space(1)))*)g,
      (unsigned int __attribute__((address_space(3)))*)l, 16, 0, 0);
}

// ---- W[z] f32 -> bf16, layout [g][kt][n][32 d-chunk-swizzled] --------------
__global__ __launch_bounds__(256) void wcvt_kernel(
    const float* __restrict__ Wq, const float* __restrict__ Wk,
    const float* __restrict__ Wv, const int* __restrict__ zp,
    short* __restrict__ Wb) {
  int z = *zp;
  int i = blockIdx.x * 256 + threadIdx.x;
  int g = i >> 15;
  int off = (i & 32767) * 8;                   // flat [n][d], d fast
  int n = off >> 9, d0 = off & 511;
  int kt = d0 >> 5, c = d0 & 31;
  int sw = ((c >> 3) ^ ((n >> 1) & 3));
  const float* src = (g == 0 ? Wq : (g == 1 ? Wk : Wv)) + (size_t)z * DIM * DIM + off;
  float4 a = *(const float4*)src, b = *(const float4*)(src + 4);
  short8 v;
  v[0]=f2bs(a.x); v[1]=f2bs(a.y); v[2]=f2bs(a.z); v[3]=f2bs(a.w);
  v[4]=f2bs(b.x); v[5]=f2bs(b.y); v[6]=f2bs(b.z); v[7]=f2bs(b.w);
  *(short8*)&Wb[((size_t)(g * 16 + kt) * 512 + n) * 32 + sw * 8] = v;
}

// ---- projection GEMM: C[m][n] = sum_d Ez[m][d] * W[n][d] -------------------
__global__ __launch_bounds__(512, 4) void proj_kernel(
    const float* __restrict__ Ez, const short* __restrict__ Wb,
    short* __restrict__ Qb, short* __restrict__ Kb, short* __restrict__ Vtb) {
  int g = blockIdx.z;
  const short* W = Wb + (size_t)g * 16 * 512 * 32;
  __shared__ short As[2][64 * 32];
  __shared__ short Bs[2][512 * 32];
  int tid = threadIdx.x, lane = tid & 63, wid = tid >> 6;
  int l15 = lane & 15, lg = lane >> 4;
  int m0 = blockIdx.x * 64;
  int sw = (l15 >> 1) & 3;
  f32x4 zero4 = {0.f, 0.f, 0.f, 0.f};
  f32x4 acc[4][4];
  #pragma unroll
  for (int mi = 0; mi < 4; mi++)
    #pragma unroll
    for (int ni = 0; ni < 4; ni++) acc[mi][ni] = zero4;

  int arow = tid >> 3, aq = tid & 7;
  int aoff = arow * 32 + (((aq >> 1) ^ ((arow >> 1) & 3)) << 3) + (aq & 1) * 4;
  const float* aptr = Ez + (size_t)(m0 + arow) * DIM + aq * 4;

  {  // prologue: stage kt=0
    float4 a = *(const float4*)aptr;
    short4v av;
    av[0]=f2bs(a.x); av[1]=f2bs(a.y); av[2]=f2bs(a.z); av[3]=f2bs(a.w);
    *(short4v*)&As[0][aoff] = av;
    #pragma unroll
    for (int ii = 0; ii < 4; ii++) {
      int s = wid * 4 + ii;
      gld16(W + s * 512 + lane * 8, &Bs[0][s * 512]);
    }
  }
  __syncthreads();

  #pragma unroll 2
  for (int kt = 0; kt < 16; kt++) {
    int cur = kt & 1;
    float4 a;
    if (kt < 15) {
      a = *(const float4*)(aptr + (kt + 1) * 32);
      #pragma unroll
      for (int ii = 0; ii < 4; ii++) {
        int s = wid * 4 + ii;
        gld16(W + (size_t)(kt + 1) * 16384 + s * 512 + lane * 8, &Bs[cur ^ 1][s * 512]);
      }
    }
    short8 af[4], bf[4];
    #pragma unroll
    for (int mi = 0; mi < 4; mi++)
      af[mi] = *(const short8*)&As[cur][(mi * 16 + l15) * 32 + ((lg ^ sw) << 3)];
    #pragma unroll
    for (int ni = 0; ni < 4; ni++)
      bf[ni] = *(const short8*)&Bs[cur][(wid * 64 + ni * 16 + l15) * 32 + ((lg ^ sw) << 3)];
    __builtin_amdgcn_s_setprio(1);
    #pragma unroll
    for (int mi = 0; mi < 4; mi++)
      #pragma unroll
      for (int ni = 0; ni < 4; ni++)
        acc[mi][ni] = __builtin_amdgcn_mfma_f32_16x16x32_bf16(af[mi], bf[ni], acc[mi][ni], 0, 0, 0);
    __builtin_amdgcn_s_setprio(0);
    if (kt < 15) {
      short4v av;
      av[0]=f2bs(a.x); av[1]=f2bs(a.y); av[2]=f2bs(a.z); av[3]=f2bs(a.w);
      *(short4v*)&As[cur ^ 1][aoff] = av;
    }
    __syncthreads();
  }

  if (g == 2) {
    #pragma unroll
    for (int mi = 0; mi < 4; mi++) {
      int gm0 = m0 + mi * 16 + lg * 4;
      int b = gm0 >> 11, l0 = gm0 & (LSEQ - 1);
      int t = l0 >> 5, c0 = l0 & 31;
      #pragma unroll
      for (int ni = 0; ni < 4; ni++) {
        int e = wid * 64 + ni * 16 + l15;
        short4v v;
        v[0]=f2bs(acc[mi][ni][0]); v[1]=f2bs(acc[mi][ni][1]);
        v[2]=f2bs(acc[mi][ni][2]); v[3]=f2bs(acc[mi][ni][3]);
        size_t idx = ((size_t)(b * 64 + t) * 512 + e) * 32
                     + (((c0 >> 3) ^ ((e >> 1) & 3)) << 3) + (c0 & 7);
        *(short4v*)&Vtb[idx] = v;   // tile-contiguous V, read-swizzle pre-baked
      }
    }
  } else {
    short* dst = (g == 0 ? Qb : Kb);
    float sc = (g == 0 ? SCALE * LOG2E : 1.0f);  // Q pre-scaled, exp2 domain
    #pragma unroll
    for (int mi = 0; mi < 4; mi++) {
      int gm0 = m0 + mi * 16 + lg * 4;
      #pragma unroll
      for (int ni = 0; ni < 4; ni++) {
        int gn = wid * 64 + ni * 16 + l15;
        #pragma unroll
        for (int r = 0; r < 4; r++)
          dst[(size_t)(gm0 + r) * DIM + gn] = f2bs(acc[mi][ni][r] * sc);
      }
    }
  }
}

// ---- flash attention (causal) ----------------------------------------------
__device__ __forceinline__ void stage_k(const short* __restrict__ Kb,
                                        short* Klbuf,
                                        int batch, int t, int wid, int lane) {
  #pragma unroll
  for (int ii = 0; ii < 4; ii++) {          // K: rows wid, wid+8, wid+16, wid+24
    int r = wid + ii * 8;                   // r&7 == wid
    const short* src = Kb + (size_t)(batch * LSEQ + t * 32 + r) * DIM + ((lane ^ wid) * 8);
    gld16(src, Klbuf + r * 512);
  }
}
__device__ __forceinline__ void stage_v(const short* __restrict__ Vtb,
                                        short* Vlbuf,
                                        int batch, int t, int wid, int lane) {
  const short* vt = Vtb + (size_t)(batch * 64 + t) * 16384;  // contiguous 32KB
  #pragma unroll
  for (int ii = 0; ii < 4; ii++) {
    int s = wid * 4 + ii;
    gld16(vt + s * 512 + lane * 8, Vlbuf + s * 512);
  }
}

__global__ __launch_bounds__(512, 2) void attn_kernel(
    const short* __restrict__ Qb, const short* __restrict__ Kb,
    const short* __restrict__ Vtb, float* __restrict__ out) {
  __shared__ short Kl[2][32 * 512];      // 64 KB dbuf
  __shared__ short Vl[2][512 * 32];      // 64 KB dbuf
  __shared__ short P_lds[2][8][16][40];  // P dbuf by t&1; 20 KB
  __shared__ float alpha_lds[2][8];
  __shared__ float dsum[128];
  int tid = threadIdx.x, lane = tid & 63, wid = tid >> 6;
  int l15 = lane & 15, lg = lane >> 4;
  int batch = blockIdx.x;
  f32x4 zero4 = {0.f, 0.f, 0.f, 0.f};
  short8 ones;
  #pragma unroll
  for (int i = 0; i < 8; i++) ones[i] = (short)0x3F80;

  // lane-const LDS offsets (shorts):
  int a0s = (l15 >> 2) & 1, b0s = l15 & 3;
  int kqE = l15 * 512 + 8 * (lg ^ b0s) + 32 * a0s;  // even-kt base (+8192 c=1)
  int kqO = l15 * 512 + 8 * (lg ^ b0s) - 32 * a0s;  // odd-kt base
  // own 256-dim V slice: e = (wid&1)*256 + et*16 + l15
  int voff = (wid & 1) * 8192 + l15 * 32 + 8 * (lg ^ ((l15 >> 1) & 3));
  short* pw = &P_lds[0][wid][lg * 4][l15];        // write: +cur*5120 +40*r (+16)
  const short* prd = &P_lds[0][0][l15][lg * 8];   // read:  +pb*5120 +640*j
  int j0 = wid & ~1;                               // PV row-group pair base

  for (int qpass = 0; qpass < 2; qpass++) {
    int qt = qpass ? (int)blockIdx.y : 15 - (int)blockIdx.y;  // long pass first
    int qb0 = qt * 128;
    int q0w = qb0 + wid * 16;
    int nt = qt * 4 + 4;

    stage_k(Kb, Kl[0], batch, 0, wid, lane);  // prologue: K(0)

    const short* qrow = Qb + (size_t)(batch * LSEQ + q0w + l15) * DIM;
    short8 qf[16];  // Q rows in regs (SCALE*LOG2E pre-folded)
    #pragma unroll
    for (int kt = 0; kt < 16; kt++) qf[kt] = *(const short8*)(qrow + kt * 32 + lg * 8);

    f32x4 oacc[2][16];  // [rowgroup j0+g][e-tile]: 32 rows x 256 dims
    #pragma unroll
    for (int i = 0; i < 2; i++)
      #pragma unroll
      for (int j = 0; j < 16; j++) oacc[i][j] = zero4;
    f32x4 dacc = zero4;   // own q-tile denominator (rows wid*16)
    float mrun = -1e30f;

    __syncthreads();  // drains prologue stage (vmcnt) + syncs

    for (int t = 0; t < nt; t++) {
      int cur = t & 1, pb = cur ^ 1;  // pb = (t-1)&1
      if (t + 1 < nt)
        stage_k(Kb, Kl[cur ^ 1], batch, t + 1, wid, lane);
      stage_v(Vtb, Vl[cur], batch, t, wid, lane);  // V(t): consumed iter t+1

      bool act = (t * 32 <= q0w + 15);
      f32x4 sacc[2] = {zero4, zero4};

      if (t > 0) {
        bool pv0 = ((t - 1) * 32 <= qb0 + j0 * 16 + 15);
        bool pv1 = ((t - 1) * 32 <= qb0 + j0 * 16 + 31);
        bool own_prev = ((t - 1) * 32 <= q0w + 15);
        float a0 = alpha_lds[pb][j0], a1 = alpha_lds[pb][j0 + 1];
        const short* vb = Vl[pb] + voff;
        const short* pbase = prd + pb * 5120;
        short8 pA0 = *(const short8*)(pbase + j0 * 640);
        short8 pA1 = *(const short8*)(pbase + (j0 + 1) * 640);
        if (pv0 && a0 != 1.0f) {
          #pragma unroll
          for (int e4 = 0; e4 < 16; e4++) {
            oacc[0][e4][0] *= a0; oacc[0][e4][1] *= a0;
            oacc[0][e4][2] *= a0; oacc[0][e4][3] *= a0;
          }
        }
        if (pv1 && a1 != 1.0f) {
          #pragma unroll
          for (int e4 = 0; e4 < 16; e4++) {
            oacc[1][e4][0] *= a1; oacc[1][e4][1] *= a1;
            oacc[1][e4][2] *= a1; oacc[1][e4][3] *= a1;
          }
        }
        __builtin_amdgcn_s_setprio(1);
        if (own_prev) {  // dacc += own P(t-1) row-sums
          short8 paw = *(const short8*)(pbase + wid * 640);
          dacc = __builtin_amdgcn_mfma_f32_16x16x32_bf16(paw, ones, dacc, 0, 0, 0);
        }
        if (act) {  // zip: QK(t) interleaved with PV(t-1)
          const short* pE = Kl[cur] + kqE;
          const short* pO = Kl[cur] + kqO;
          #pragma unroll
          for (int u = 0; u < 8; u++) {
            int kt = 2 * u;
            short8 k0 = *(const short8*)(pE + 32 * kt);
            short8 k1 = *(const short8*)(pE + 8192 + 32 * kt);
            sacc[0] = __builtin_amdgcn_mfma_f32_16x16x32_bf16(qf[kt], k0, sacc[0], 0, 0, 0);
            sacc[1] = __builtin_amdgcn_mfma_f32_16x16x32_bf16(qf[kt], k1, sacc[1], 0, 0, 0);
            short8 bv0 = *(const short8*)(vb + (2 * u) * 512);
            short8 bv1 = *(const short8*)(vb + (2 * u + 1) * 512);
            if (pv0) {
              oacc[0][2 * u] = __builtin_amdgcn_mfma_f32_16x16x32_bf16(pA0, bv0, oacc[0][2 * u], 0, 0, 0);
              oacc[0][2 * u + 1] = __builtin_amdgcn_mfma_f32_16x16x32_bf16(pA0, bv1, oacc[0][2 * u + 1], 0, 0, 0);
            }
            short8 k2 = *(const short8*)(pO + 32 * (kt + 1));
            short8 k3 = *(const short8*)(pO + 8192 + 32 * (kt + 1));
            sacc[0] = __builtin_amdgcn_mfma_f32_16x16x32_bf16(qf[kt + 1], k2, sacc[0], 0, 0, 0);
            sacc[1] = __builtin_amdgcn_mfma_f32_16x16x32_bf16(qf[kt + 1], k3, sacc[1], 0, 0, 0);
            if (pv1) {
              oacc[1][2 * u] = __builtin_amdgcn_mfma_f32_16x16x32_bf16(pA1, bv0, oacc[1][2 * u], 0, 0, 0);
              oacc[1][2 * u + 1] = __builtin_amdgcn_mfma_f32_16x16x32_bf16(pA1, bv1, oacc[1][2 * u + 1], 0, 0, 0);
            }
          }
        } else {  // PV(t-1) only
          #pragma unroll
          for (int e4 = 0; e4 < 16; e4++) {
            short8 bv = *(const short8*)(vb + e4 * 512);
            if (pv0)
              oacc[0][e4] = __builtin_amdgcn_mfma_f32_16x16x32_bf16(pA0, bv, oacc[0][e4], 0, 0, 0);
            if (pv1)
              oacc[1][e4] = __builtin_amdgcn_mfma_f32_16x16x32_bf16(pA1, bv, oacc[1][e4], 0, 0, 0);
          }
        }
        __builtin_amdgcn_s_setprio(0);
      } else if (act) {  // t == 0: QK only
        const short* pE = Kl[cur] + kqE;
        const short* pO = Kl[cur] + kqO;
        __builtin_amdgcn_s_setprio(1);
        #pragma unroll
        for (int kt = 0; kt < 16; kt += 2) {
          short8 k0 = *(const short8*)(pE + 32 * kt);
          short8 k1 = *(const short8*)(pE + 8192 + 32 * kt);
          sacc[0] = __builtin_amdgcn_mfma_f32_16x16x32_bf16(qf[kt], k0, sacc[0], 0, 0, 0);
          sacc[1] = __builtin_amdgcn_mfma_f32_16x16x32_bf16(qf[kt], k1, sacc[1], 0, 0, 0);
          short8 k2 = *(const short8*)(pO + 32 * (kt + 1));
          short8 k3 = *(const short8*)(pO + 8192 + 32 * (kt + 1));
          sacc[0] = __builtin_amdgcn_mfma_f32_16x16x32_bf16(qf[kt + 1], k2, sacc[0], 0, 0, 0);
          sacc[1] = __builtin_amdgcn_mfma_f32_16x16x32_bf16(qf[kt + 1], k3, sacc[1], 0, 0, 0);
        }
        __builtin_amdgcn_s_setprio(0);
      }

      if (act) {  // softmax(t): mask, lazy max (rescales dacc only), publish
        if (t * 32 + 31 > q0w) {
          #pragma unroll
          for (int r = 0; r < 4; r++) {
            int q = q0w + lg * 4 + r;
            if (t * 32 + l15 > q) sacc[0][r] = -1e30f;
            if (t * 32 + 16 + l15 > q) sacc[1][r] = -1e30f;
          }
        }
        float lm = fmaxf(
            fmaxf(fmaxf(sacc[0][0], sacc[0][1]), fmaxf(sacc[0][2], sacc[0][3])),
            fmaxf(fmaxf(sacc[1][0], sacc[1][1]), fmaxf(sacc[1][2], sacc[1][3])));
        float alpha_t = 1.0f;
        if (__any(lm > mrun + 11.5f)) {
          float mx = lm;
          #pragma unroll
          for (int off = 1; off < 64; off <<= 1) mx = fmaxf(mx, __shfl_xor(mx, off, 64));
          alpha_t = exp2f(mrun - mx);
          mrun = mx;
          dacc[0] *= alpha_t; dacc[1] *= alpha_t;
          dacc[2] *= alpha_t; dacc[3] *= alpha_t;
        }
        int pboff = cur * 5120;
        #pragma unroll
        for (int r = 0; r < 4; r++) {
          pw[pboff + r * 40] = f2bs(exp2f(sacc[0][r] - mrun));
          pw[pboff + r * 40 + 16] = f2bs(exp2f(sacc[1][r] - mrun));
        }
        if (lane == 0) alpha_lds[cur][wid] = alpha_t;
      }
      __syncthreads();  // P(t)/alpha(t) visible; vmcnt drained; buffers released
    }

    {  // drain: PV(nt-1), buffers (nt-1)&1
      int pb = (nt - 1) & 1;
      const short* vb = Vl[pb] + voff;
      const short* pbase = prd + pb * 5120;
      if ((nt - 1) * 32 <= q0w + 15) {
        short8 paw = *(const short8*)(pbase + wid * 640);
        dacc = __builtin_amdgcn_mfma_f32_16x16x32_bf16(paw, ones, dacc, 0, 0, 0);
      }
      #pragma unroll
      for (int g = 0; g < 2; g++) {
        int j = j0 + g;
        if ((nt - 1) * 32 <= qb0 + j * 16 + 15) {
          short8 pA = *(const short8*)(pbase + j * 640);
          float a = alpha_lds[pb][j];
          if (a != 1.0f) {
            #pragma unroll
            for (int e4 = 0; e4 < 16; e4++) {
              oacc[g][e4][0] *= a; oacc[g][e4][1] *= a;
              oacc[g][e4][2] *= a; oacc[g][e4][3] *= a;
            }
          }
          #pragma unroll
          for (int e4 = 0; e4 < 16; e4++) {
            short8 bv = *(const short8*)(vb + e4 * 512);
            oacc[g][e4] = __builtin_amdgcn_mfma_f32_16x16x32_bf16(pA, bv, oacc[g][e4], 0, 0, 0);
          }
        }
      }
    }
    // epilogue: broadcast denominators, write pair rows x own dim slice
    if (l15 == 0) {
      #pragma unroll
      for (int r = 0; r < 4; r++) dsum[wid * 16 + lg * 4 + r] = dacc[r];
    }
    __syncthreads();
    #pragma unroll
    for (int g = 0; g < 2; g++)
      #pragma unroll
      for (int r = 0; r < 4; r++) {
        float inv = 1.0f / dsum[(j0 + g) * 16 + lg * 4 + r];
        int q = qb0 + (j0 + g) * 16 + lg * 4 + r;
        #pragma unroll
        for (int e4 = 0; e4 < 16; e4++)
          out[((size_t)(batch * LSEQ + q)) * DIM + (wid & 1) * 256 + e4 * 16 + l15] =
              oacc[g][e4][r] * inv;
      }
    __syncthreads();  // LDS reuse safe before next qpass
  }
}

extern "C" void kernel_launch(void* const* d_in, const int* in_sizes, int n_in,
                              void* d_out, int out_size, void* d_ws, size_t ws_size,
                              hipStream_t stream) {
  const float* Ez = (const float*)d_in[0];
  const float* Wq = (const float*)d_in[1];
  const float* Wk = (const float*)d_in[2];
  const float* Wv = (const float*)d_in[3];
  const int* zp = (const int*)d_in[4];
  float* out = (float*)d_out;
  short* Qb = (short*)d_ws;
  short* Kb = Qb + (size_t)NB * LSEQ * DIM;
  short* Vtb = Kb + (size_t)NB * LSEQ * DIM;
  short* Wb = (short*)d_out;  // scratch: proj completes before attn writes out
  hipLaunchKernelGGL(wcvt_kernel, dim3(384), dim3(256), 0, stream,
                     Wq, Wk, Wv, zp, Wb);
  hipLaunchKernelGGL(proj_kernel, dim3(1024, 1, 3), dim3(512), 0, stream,
                     Ez, Wb, Qb, Kb, Vtb);
  hipLaunchKernelGGL(attn_kernel, dim3(32, 8), dim3(512), 0, stream,
                     Qb, Kb, Vtb, out);
}

// Round 18
// 466.289 us; speedup vs baseline: 1.1055x; 1.0682x over previous
//
#include <hip/hip_runtime.h>
#include <hip/hip_bf16.h>

// SelfAttention: out = softmax(causal((Ez Wq^T)(Ez Wk^T)^T / sqrt(512))) (Ez Wv^T)
// B=32, L=2048, DIM=512. f32 in/out; bf16 MFMA internally.
// ws: Qb (bf16, Q*SCALE*LOG2E), Kb (bf16), Vtb (bf16, [b][t][e][32] tile-contig,
// chunk-XOR pre-baked). Wb (bf16 [g][kt][n][32], swizzled) in d_out scratch.
// R18 = attn frozen at R15 (proven 270us); proj MERGED: one block stages its
// 64-row Ez tile to LDS once (all 16 k-slabs) and runs g=0,1,2 B-loops against
// it -> Ez HBM reads 384->128 MB, A-stage cost paid once.

typedef __attribute__((ext_vector_type(8))) short short8;
typedef __attribute__((ext_vector_type(4))) short short4v;
typedef __attribute__((ext_vector_type(4))) float f32x4;

#define DIM 512
#define LSEQ 2048
#define NB 32
#define SCALE 0.04419417382415922f
#define LOG2E 1.4426950408889634f

__device__ __forceinline__ short f2bs(float f) {
  __hip_bfloat16 h = __float2bfloat16(f);
  return __builtin_bit_cast(short, h);
}

__device__ __forceinline__ void gld16(const void* g, void* l) {
  __builtin_amdgcn_global_load_lds(
      (const unsigned int __attribute__((address_space(1)))*)g,
      (unsigned int __attribute__((address_space(3)))*)l, 16, 0, 0);
}

// ---- W[z] f32 -> bf16, layout [g][kt][n][32 d-chunk-swizzled] --------------
__global__ __launch_bounds__(256) void wcvt_kernel(
    const float* __restrict__ Wq, const float* __restrict__ Wk,
    const float* __restrict__ Wv, const int* __restrict__ zp,
    short* __restrict__ Wb) {
  int z = *zp;
  int i = blockIdx.x * 256 + threadIdx.x;
  int g = i >> 15;
  int off = (i & 32767) * 8;                   // flat [n][d], d fast
  int n = off >> 9, d0 = off & 511;
  int kt = d0 >> 5, c = d0 & 31;
  int sw = ((c >> 3) ^ ((n >> 1) & 3));
  const float* src = (g == 0 ? Wq : (g == 1 ? Wk : Wv)) + (size_t)z * DIM * DIM + off;
  float4 a = *(const float4*)src, b = *(const float4*)(src + 4);
  short8 v;
  v[0]=f2bs(a.x); v[1]=f2bs(a.y); v[2]=f2bs(a.z); v[3]=f2bs(a.w);
  v[4]=f2bs(b.x); v[5]=f2bs(b.y); v[6]=f2bs(b.z); v[7]=f2bs(b.w);
  *(short8*)&Wb[((size_t)(g * 16 + kt) * 512 + n) * 32 + sw * 8] = v;
}

// ---- merged projection GEMM: for g in {q,k,v}: C = Ez * W[g]^T -------------
// Block = 64 Ez rows. A (Ez bf16, swizzled, all 16 k-slabs) staged ONCE into
// 64 KB LDS; then 3 sequential B-panel loops (one per g) with dbuf gld16.
__global__ __launch_bounds__(512, 2) void proj_kernel(
    const float* __restrict__ Ez, const short* __restrict__ Wb,
    short* __restrict__ Qb, short* __restrict__ Kb, short* __restrict__ Vtb) {
  __shared__ short As[16 * 2048];     // 64 KB: [kt][64 rows][32 cols] swizzled
  __shared__ short Bs[2][512 * 32];   // 64 KB dbuf
  int tid = threadIdx.x, lane = tid & 63, wid = tid >> 6;
  int l15 = lane & 15, lg = lane >> 4;
  int m0 = blockIdx.x * 64;
  int sw = (l15 >> 1) & 3;
  f32x4 zero4 = {0.f, 0.f, 0.f, 0.f};

  int arow = tid >> 3, aq = tid & 7;
  int aoff = arow * 32 + (((aq >> 1) ^ ((arow >> 1) & 3)) << 3) + (aq & 1) * 4;
  const float* aptr = Ez + (size_t)(m0 + arow) * DIM + aq * 4;

  // stage A: all 16 k-slabs, once
  #pragma unroll 4
  for (int kt = 0; kt < 16; kt++) {
    float4 a = *(const float4*)(aptr + kt * 32);
    short4v av;
    av[0]=f2bs(a.x); av[1]=f2bs(a.y); av[2]=f2bs(a.z); av[3]=f2bs(a.w);
    *(short4v*)&As[kt * 2048 + aoff] = av;
  }

  for (int g = 0; g < 3; g++) {
    const short* W = Wb + (size_t)g * 16 * 512 * 32;
    f32x4 acc[4][4];
    #pragma unroll
    for (int mi = 0; mi < 4; mi++)
      #pragma unroll
      for (int ni = 0; ni < 4; ni++) acc[mi][ni] = zero4;

    {  // prologue: stage B(g,0)
      #pragma unroll
      for (int ii = 0; ii < 4; ii++) {
        int s = wid * 4 + ii;
        gld16(W + s * 512 + lane * 8, &Bs[0][s * 512]);
      }
    }
    __syncthreads();  // A ready (g=0) / prev-g drained; B0 ready

    #pragma unroll 2
    for (int kt = 0; kt < 16; kt++) {
      int cur = kt & 1;
      if (kt < 15) {
        #pragma unroll
        for (int ii = 0; ii < 4; ii++) {
          int s = wid * 4 + ii;
          gld16(W + (size_t)(kt + 1) * 16384 + s * 512 + lane * 8, &Bs[cur ^ 1][s * 512]);
        }
      }
      short8 af[4], bf[4];
      #pragma unroll
      for (int mi = 0; mi < 4; mi++)
        af[mi] = *(const short8*)&As[kt * 2048 + (mi * 16 + l15) * 32 + ((lg ^ sw) << 3)];
      #pragma unroll
      for (int ni = 0; ni < 4; ni++)
        bf[ni] = *(const short8*)&Bs[cur][(wid * 64 + ni * 16 + l15) * 32 + ((lg ^ sw) << 3)];
      __builtin_amdgcn_s_setprio(1);
      #pragma unroll
      for (int mi = 0; mi < 4; mi++)
        #pragma unroll
        for (int ni = 0; ni < 4; ni++)
          acc[mi][ni] = __builtin_amdgcn_mfma_f32_16x16x32_bf16(af[mi], bf[ni], acc[mi][ni], 0, 0, 0);
      __builtin_amdgcn_s_setprio(0);
      __syncthreads();
    }

    if (g == 2) {
      #pragma unroll
      for (int mi = 0; mi < 4; mi++) {
        int gm0 = m0 + mi * 16 + lg * 4;
        int b = gm0 >> 11, l0 = gm0 & (LSEQ - 1);
        int t = l0 >> 5, c0 = l0 & 31;
        #pragma unroll
        for (int ni = 0; ni < 4; ni++) {
          int e = wid * 64 + ni * 16 + l15;
          short4v v;
          v[0]=f2bs(acc[mi][ni][0]); v[1]=f2bs(acc[mi][ni][1]);
          v[2]=f2bs(acc[mi][ni][2]); v[3]=f2bs(acc[mi][ni][3]);
          size_t idx = ((size_t)(b * 64 + t) * 512 + e) * 32
                       + (((c0 >> 3) ^ ((e >> 1) & 3)) << 3) + (c0 & 7);
          *(short4v*)&Vtb[idx] = v;   // tile-contiguous V, read-swizzle pre-baked
        }
      }
    } else {
      short* dst = (g == 0 ? Qb : Kb);
      float sc = (g == 0 ? SCALE * LOG2E : 1.0f);  // Q pre-scaled, exp2 domain
      #pragma unroll
      for (int mi = 0; mi < 4; mi++) {
        int gm0 = m0 + mi * 16 + lg * 4;
        #pragma unroll
        for (int ni = 0; ni < 4; ni++) {
          int gn = wid * 64 + ni * 16 + l15;
          #pragma unroll
          for (int r = 0; r < 4; r++)
            dst[(size_t)(gm0 + r) * DIM + gn] = f2bs(acc[mi][ni][r] * sc);
        }
      }
    }
  }
}

// ---- flash attention (causal) — R15 structure, frozen ----------------------
__device__ __forceinline__ void stage_k(const short* __restrict__ Kb,
                                        short* Klbuf,
                                        int batch, int t, int wid, int lane) {
  #pragma unroll
  for (int ii = 0; ii < 4; ii++) {          // K: rows wid, wid+8, wid+16, wid+24
    int r = wid + ii * 8;                   // r&7 == wid
    const short* src = Kb + (size_t)(batch * LSEQ + t * 32 + r) * DIM + ((lane ^ wid) * 8);
    gld16(src, Klbuf + r * 512);
  }
}
__device__ __forceinline__ void stage_v(const short* __restrict__ Vtb,
                                        short* Vlbuf,
                                        int batch, int t, int wid, int lane) {
  const short* vt = Vtb + (size_t)(batch * 64 + t) * 16384;  // contiguous 32KB
  #pragma unroll
  for (int ii = 0; ii < 4; ii++) {
    int s = wid * 4 + ii;
    gld16(vt + s * 512 + lane * 8, Vlbuf + s * 512);
  }
}

__global__ __launch_bounds__(512, 2) void attn_kernel(
    const short* __restrict__ Qb, const short* __restrict__ Kb,
    const short* __restrict__ Vtb, float* __restrict__ out) {
  __shared__ short Kl[2][32 * 512];   // 64 KB dbuf
  __shared__ short Vl[2][512 * 32];   // 64 KB dbuf
  __shared__ short P_lds[8][16][40];  // per-wave P transpose; 16B-aligned rows
  int tid = threadIdx.x, lane = tid & 63, wid = tid >> 6;
  int l15 = lane & 15, lg = lane >> 4;
  int batch = blockIdx.x;
  f32x4 zero4 = {0.f, 0.f, 0.f, 0.f};
  short8 ones;
  #pragma unroll
  for (int i = 0; i < 8; i++) ones[i] = (short)0x3F80;

  // lane-const LDS offsets (shorts):
  int a0 = (l15 >> 2) & 1, b0 = l15 & 3;
  int kqE = l15 * 512 + 8 * (lg ^ b0) + 32 * a0;  // even-kt base (+8192 for c=1)
  int kqO = l15 * 512 + 8 * (lg ^ b0) - 32 * a0;  // odd-kt base
  int voff = l15 * 32 + 8 * (lg ^ ((l15 >> 1) & 3));  // V base (+512*et)
  short* pw = &P_lds[wid][lg * 4][l15];               // P write (+40*r, +16*c)
  const short* pr = &P_lds[wid][l15][lg * 8];         // P read (A-frag, aligned)

  for (int qpass = 0; qpass < 2; qpass++) {
    int qt = qpass ? (int)blockIdx.y : 15 - (int)blockIdx.y;  // long pass first
    int qb0 = qt * 128;
    int q0w = qb0 + wid * 16;
    int nt = qt * 4 + 4;

    stage_k(Kb, Kl[0], batch, 0, wid, lane);  // prologue: K(0) only

    const short* qrow = Qb + (size_t)(batch * LSEQ + q0w + l15) * DIM;
    short8 qf[16];  // Q rows in regs (SCALE*LOG2E pre-folded)
    #pragma unroll
    for (int kt = 0; kt < 16; kt++) qf[kt] = *(const short8*)(qrow + kt * 32 + lg * 8);

    f32x4 oacc[32];
    #pragma unroll
    for (int i = 0; i < 32; i++) oacc[i] = zero4;
    f32x4 dacc = zero4;   // per-row softmax denominator (via ones-MFMA)
    float mrun = -1e30f;  // wave-uniform running max (exp2 domain)
    short8 pa;            // P fragment of tile t-1 (valid when act(t-1))

    __syncthreads();  // drains prologue stage (vmcnt) + syncs

    for (int t = 0; t < nt; t++) {
      int cur = t & 1;
      if (t + 1 < nt)
        stage_k(Kb, Kl[cur ^ 1], batch, t + 1, wid, lane);
      stage_v(Vtb, Vl[cur], batch, t, wid, lane);  // V(t): consumed iter t+1

      bool act = (t * 32 <= q0w + 15);
      bool actp = (t > 0) && ((t - 1) * 32 <= q0w + 15);
      f32x4 sacc[2] = {zero4, zero4};
      if (act && actp) {
        // merged block: QK(t) interleaved with PV(t-1) (independent streams)
        const short* pE = Kl[cur] + kqE;
        const short* pO = Kl[cur] + kqO;
        const short* vb = Vl[cur ^ 1] + voff;
        __builtin_amdgcn_s_setprio(1);
        dacc = __builtin_amdgcn_mfma_f32_16x16x32_bf16(pa, ones, dacc, 0, 0, 0);
        #pragma unroll
        for (int kt = 0; kt < 16; kt += 2) {
          short8 k0 = *(const short8*)(pE + 32 * kt);
          short8 k1 = *(const short8*)(pE + 8192 + 32 * kt);
          sacc[0] = __builtin_amdgcn_mfma_f32_16x16x32_bf16(qf[kt], k0, sacc[0], 0, 0, 0);
          sacc[1] = __builtin_amdgcn_mfma_f32_16x16x32_bf16(qf[kt], k1, sacc[1], 0, 0, 0);
          short8 v0 = *(const short8*)(vb + (kt * 2) * 512);
          short8 v1 = *(const short8*)(vb + (kt * 2 + 1) * 512);
          oacc[kt * 2] = __builtin_amdgcn_mfma_f32_16x16x32_bf16(pa, v0, oacc[kt * 2], 0, 0, 0);
          oacc[kt * 2 + 1] = __builtin_amdgcn_mfma_f32_16x16x32_bf16(pa, v1, oacc[kt * 2 + 1], 0, 0, 0);
          short8 k2 = *(const short8*)(pO + 32 * (kt + 1));
          short8 k3 = *(const short8*)(pO + 8192 + 32 * (kt + 1));
          sacc[0] = __builtin_amdgcn_mfma_f32_16x16x32_bf16(qf[kt + 1], k2, sacc[0], 0, 0, 0);
          sacc[1] = __builtin_amdgcn_mfma_f32_16x16x32_bf16(qf[kt + 1], k3, sacc[1], 0, 0, 0);
          short8 v2 = *(const short8*)(vb + (kt * 2 + 2) * 512);
          short8 v3 = *(const short8*)(vb + (kt * 2 + 3) * 512);
          oacc[kt * 2 + 2] = __builtin_amdgcn_mfma_f32_16x16x32_bf16(pa, v2, oacc[kt * 2 + 2], 0, 0, 0);
          oacc[kt * 2 + 3] = __builtin_amdgcn_mfma_f32_16x16x32_bf16(pa, v3, oacc[kt * 2 + 3], 0, 0, 0);
        }
        __builtin_amdgcn_s_setprio(0);
      } else if (act) {  // t == 0: QK only
        const short* pE = Kl[cur] + kqE;
        const short* pO = Kl[cur] + kqO;
        __builtin_amdgcn_s_setprio(1);
        #pragma unroll
        for (int kt = 0; kt < 16; kt += 2) {
          short8 k0 = *(const short8*)(pE + 32 * kt);
          short8 k1 = *(const short8*)(pE + 8192 + 32 * kt);
          sacc[0] = __builtin_amdgcn_mfma_f32_16x16x32_bf16(qf[kt], k0, sacc[0], 0, 0, 0);
          sacc[1] = __builtin_amdgcn_mfma_f32_16x16x32_bf16(qf[kt], k1, sacc[1], 0, 0, 0);
          short8 k2 = *(const short8*)(pO + 32 * (kt + 1));
          short8 k3 = *(const short8*)(pO + 8192 + 32 * (kt + 1));
          sacc[0] = __builtin_amdgcn_mfma_f32_16x16x32_bf16(qf[kt + 1], k2, sacc[0], 0, 0, 0);
          sacc[1] = __builtin_amdgcn_mfma_f32_16x16x32_bf16(qf[kt + 1], k3, sacc[1], 0, 0, 0);
        }
        __builtin_amdgcn_s_setprio(0);
      } else if (actp) {  // transition tile: PV(t-1) only
        const short* vb = Vl[cur ^ 1] + voff;
        __builtin_amdgcn_s_setprio(1);
        dacc = __builtin_amdgcn_mfma_f32_16x16x32_bf16(pa, ones, dacc, 0, 0, 0);
        #pragma unroll
        for (int et = 0; et < 32; et++) {
          short8 bv = *(const short8*)(vb + et * 512);
          oacc[et] = __builtin_amdgcn_mfma_f32_16x16x32_bf16(pa, bv, oacc[et], 0, 0, 0);
        }
        __builtin_amdgcn_s_setprio(0);
      }
      if (act) {  // softmax(t) -> P_lds -> pa (regs) for next iter's PV
        if (t * 32 + 31 > q0w) {  // diagonal tiles only: causal mask
          #pragma unroll
          for (int r = 0; r < 4; r++) {
            int q = q0w + lg * 4 + r;
            if (t * 32 + l15 > q) sacc[0][r] = -1e30f;
            if (t * 32 + 16 + l15 > q) sacc[1][r] = -1e30f;
          }
        }
        float lm = fmaxf(
            fmaxf(fmaxf(sacc[0][0], sacc[0][1]), fmaxf(sacc[0][2], sacc[0][3])),
            fmaxf(fmaxf(sacc[1][0], sacc[1][1]), fmaxf(sacc[1][2], sacc[1][3])));
        if (__any(lm > mrun + 11.5f)) {  // rare: raise the wave max
          float mx = lm;
          #pragma unroll
          for (int off = 1; off < 64; off <<= 1) mx = fmaxf(mx, __shfl_xor(mx, off, 64));
          float alpha = exp2f(mrun - mx);
          mrun = mx;
          dacc[0] *= alpha; dacc[1] *= alpha; dacc[2] *= alpha; dacc[3] *= alpha;
          #pragma unroll
          for (int et = 0; et < 32; et++) {
            oacc[et][0] *= alpha; oacc[et][1] *= alpha;
            oacc[et][2] *= alpha; oacc[et][3] *= alpha;
          }
        }
        #pragma unroll
        for (int r = 0; r < 4; r++) {
          pw[r * 40] = f2bs(exp2f(sacc[0][r] - mrun));
          pw[r * 40 + 16] = f2bs(exp2f(sacc[1][r] - mrun));
        }
        pa = *(const short8*)pr;  // wave-local RAW
      }
      __syncthreads();  // drains prefetch (vmcnt) + releases buffers
    }
    // drain: PV(nt-1) for waves active at the last tile
    if ((nt - 1) * 32 <= q0w + 15) {
      const short* vb = Vl[(nt - 1) & 1] + voff;
      dacc = __builtin_amdgcn_mfma_f32_16x16x32_bf16(pa, ones, dacc, 0, 0, 0);
      #pragma unroll
      for (int et = 0; et < 32; et++) {
        short8 bv = *(const short8*)(vb + et * 512);
        oacc[et] = __builtin_amdgcn_mfma_f32_16x16x32_bf16(pa, bv, oacc[et], 0, 0, 0);
      }
    }
    // epilogue: per-wave divide by denominator, write 16 q-rows x 512 dims
    float inv[4];
    #pragma unroll
    for (int r = 0; r < 4; r++) inv[r] = 1.0f / dacc[r];
    #pragma unroll
    for (int et = 0; et < 32; et++)
      #pragma unroll
      for (int r = 0; r < 4; r++) {
        int q = q0w + lg * 4 + r;
        out[((size_t)(batch * LSEQ + q)) * DIM + et * 16 + l15] = oacc[et][r] * inv[r];
      }
    __syncthreads();  // LDS reuse safe before next qpass
  }
}

extern "C" void kernel_launch(void* const* d_in, const int* in_sizes, int n_in,
                              void* d_out, int out_size, void* d_ws, size_t ws_size,
                              hipStream_t stream) {
  const float* Ez = (const float*)d_in[0];
  const float* Wq = (const float*)d_in[1];
  const float* Wk = (const float*)d_in[2];
  const float* Wv = (const float*)d_in[3];
  const int* zp = (const int*)d_in[4];
  float* out = (float*)d_out;
  short* Qb = (short*)d_ws;
  short* Kb = Qb + (size_t)NB * LSEQ * DIM;
  short* Vtb = Kb + (size_t)NB * LSEQ * DIM;
  short* Wb = (short*)d_out;  // scratch: proj completes before attn writes out
  hipLaunchKernelGGL(wcvt_kernel, dim3(384), dim3(256), 0, stream,
                     Wq, Wk, Wv, zp, Wb);
  hipLaunchKernelGGL(proj_kernel, dim3(1024), dim3(512), 0, stream,
                     Ez, Wb, Qb, Kb, Vtb);
  hipLaunchKernelGGL(attn_kernel, dim3(32, 8), dim3(512), 0, stream,
                     Qb, Kb, Vtb, out);
}

// Round 19
// 405.004 us; speedup vs baseline: 1.2728x; 1.1513x over previous
//
#include <hip/hip_runtime.h>
#include <hip/hip_bf16.h>

// SelfAttention: out = softmax(causal((Ez Wq^T)(Ez Wk^T)^T / sqrt(512))) (Ez Wv^T)
// B=32, L=2048, DIM=512. f32 in/out; bf16 MFMA internally.
// ws: Qb (bf16, Q*SCALE*LOG2E), Kb (bf16), Vtb (bf16, [b][t][e][32] tile-contig,
// chunk-XOR pre-baked). d_out scratch: Wb (bf16 [g][kt][n][32] swizzled) +
// Ezb (bf16 [mt][kt][64][32], A-swizzle baked).
// R19 = attn frozen at R15 (270us); proj reverted to R12 split structure but
// A staged via gld16 from pre-converted Ezb (no f32 load/cvt/ds_write in loop).

typedef __attribute__((ext_vector_type(8))) short short8;
typedef __attribute__((ext_vector_type(4))) short short4v;
typedef __attribute__((ext_vector_type(4))) float f32x4;

#define DIM 512
#define LSEQ 2048
#define NB 32
#define SCALE 0.04419417382415922f
#define LOG2E 1.4426950408889634f

__device__ __forceinline__ short f2bs(float f) {
  __hip_bfloat16 h = __float2bfloat16(f);
  return __builtin_bit_cast(short, h);
}

__device__ __forceinline__ void gld16(const void* g, void* l) {
  __builtin_amdgcn_global_load_lds(
      (const unsigned int __attribute__((address_space(1)))*)g,
      (unsigned int __attribute__((address_space(3)))*)l, 16, 0, 0);
}

// ---- convert W[z] AND Ez to bf16 (swizzles pre-baked) ----------------------
// i < 98304: W path -> Wb[g][kt][n][32]. else: Ez path -> Ezb[mt][kt][64][32].
__global__ __launch_bounds__(256) void wcvt_kernel(
    const float* __restrict__ Wq, const float* __restrict__ Wk,
    const float* __restrict__ Wv, const int* __restrict__ zp,
    const float* __restrict__ Ez,
    short* __restrict__ Wb, short* __restrict__ Ezb) {
  int z = *zp;
  int i = blockIdx.x * 256 + threadIdx.x;
  if (i < 98304) {  // W: 3 x 512x512 / 8
    int g = i >> 15;
    int off = (i & 32767) * 8;                 // flat [n][d], d fast
    int n = off >> 9, d0 = off & 511;
    int kt = d0 >> 5, c = d0 & 31;
    int sw = ((c >> 3) ^ ((n >> 1) & 3));
    const float* src = (g == 0 ? Wq : (g == 1 ? Wk : Wv)) + (size_t)z * DIM * DIM + off;
    float4 a = *(const float4*)src, b = *(const float4*)(src + 4);
    short8 v;
    v[0]=f2bs(a.x); v[1]=f2bs(a.y); v[2]=f2bs(a.z); v[3]=f2bs(a.w);
    v[4]=f2bs(b.x); v[5]=f2bs(b.y); v[6]=f2bs(b.z); v[7]=f2bs(b.w);
    *(short8*)&Wb[((size_t)(g * 16 + kt) * 512 + n) * 32 + sw * 8] = v;
  } else {  // Ez: 32*2048*512 / 8 elems
    size_t j = (size_t)(i - 98304);
    size_t off = j * 8;                        // flat [m][d], d fast
    int m = (int)(off >> 9), d0 = (int)(off & 511);
    int kt = d0 >> 5, c = d0 & 31;
    int mt = m >> 6, mr = m & 63;
    const float* src = Ez + off;
    float4 a = *(const float4*)src, b = *(const float4*)(src + 4);
    short8 v;
    v[0]=f2bs(a.x); v[1]=f2bs(a.y); v[2]=f2bs(a.z); v[3]=f2bs(a.w);
    v[4]=f2bs(b.x); v[5]=f2bs(b.y); v[6]=f2bs(b.z); v[7]=f2bs(b.w);
    size_t idx = (((size_t)mt * 16 + kt) * 64 + mr) * 32
                 + (((c >> 3) ^ ((mr >> 1) & 3)) << 3);  // A-swizzle baked (c&7==0)
    *(short8*)&Ezb[idx] = v;
  }
}

// ---- projection GEMM: C[m][n] = sum_d Ez[m][d] * W[n][d] -------------------
// BM=64, BN=512, BK=32; A via gld16 from Ezb (bf16, pre-swizzled) — kt-loop is
// pure gld16 staging + ds_read frags + MFMA. 2 blocks/CU.
__global__ __launch_bounds__(512, 4) void proj_kernel(
    const short* __restrict__ Ezb, const short* __restrict__ Wb,
    short* __restrict__ Qb, short* __restrict__ Kb, short* __restrict__ Vtb) {
  int g = blockIdx.z;
  const short* W = Wb + (size_t)g * 16 * 512 * 32;
  const short* EA = Ezb + (size_t)blockIdx.x * 16 * 2048;  // this m-tile's slabs
  __shared__ short As[2][2048];       // 8 KB dbuf
  __shared__ short Bs[2][512 * 32];   // 64 KB dbuf
  int tid = threadIdx.x, lane = tid & 63, wid = tid >> 6;
  int l15 = lane & 15, lg = lane >> 4;
  int m0 = blockIdx.x * 64;
  int sw = (l15 >> 1) & 3;
  f32x4 zero4 = {0.f, 0.f, 0.f, 0.f};
  f32x4 acc[4][4];
  #pragma unroll
  for (int mi = 0; mi < 4; mi++)
    #pragma unroll
    for (int ni = 0; ni < 4; ni++) acc[mi][ni] = zero4;

  {  // prologue: stage A(0) (waves 0-3) + B(0)
    if (wid < 4) gld16(EA + wid * 512 + lane * 8, &As[0][wid * 512]);
    #pragma unroll
    for (int ii = 0; ii < 4; ii++) {
      int s = wid * 4 + ii;
      gld16(W + s * 512 + lane * 8, &Bs[0][s * 512]);
    }
  }
  __syncthreads();

  #pragma unroll 2
  for (int kt = 0; kt < 16; kt++) {
    int cur = kt & 1;
    if (kt < 15) {
      if (wid < 4)
        gld16(EA + (size_t)(kt + 1) * 2048 + wid * 512 + lane * 8, &As[cur ^ 1][wid * 512]);
      #pragma unroll
      for (int ii = 0; ii < 4; ii++) {
        int s = wid * 4 + ii;
        gld16(W + (size_t)(kt + 1) * 16384 + s * 512 + lane * 8, &Bs[cur ^ 1][s * 512]);
      }
    }
    short8 af[4], bf[4];
    #pragma unroll
    for (int mi = 0; mi < 4; mi++)
      af[mi] = *(const short8*)&As[cur][(mi * 16 + l15) * 32 + ((lg ^ sw) << 3)];
    #pragma unroll
    for (int ni = 0; ni < 4; ni++)
      bf[ni] = *(const short8*)&Bs[cur][(wid * 64 + ni * 16 + l15) * 32 + ((lg ^ sw) << 3)];
    __builtin_amdgcn_s_setprio(1);
    #pragma unroll
    for (int mi = 0; mi < 4; mi++)
      #pragma unroll
      for (int ni = 0; ni < 4; ni++)
        acc[mi][ni] = __builtin_amdgcn_mfma_f32_16x16x32_bf16(af[mi], bf[ni], acc[mi][ni], 0, 0, 0);
    __builtin_amdgcn_s_setprio(0);
    __syncthreads();  // drains gld16 prefetch (vmcnt), releases buffers
  }

  if (g == 2) {
    #pragma unroll
    for (int mi = 0; mi < 4; mi++) {
      int gm0 = m0 + mi * 16 + lg * 4;
      int b = gm0 >> 11, l0 = gm0 & (LSEQ - 1);
      int t = l0 >> 5, c0 = l0 & 31;
      #pragma unroll
      for (int ni = 0; ni < 4; ni++) {
        int e = wid * 64 + ni * 16 + l15;
        short4v v;
        v[0]=f2bs(acc[mi][ni][0]); v[1]=f2bs(acc[mi][ni][1]);
        v[2]=f2bs(acc[mi][ni][2]); v[3]=f2bs(acc[mi][ni][3]);
        size_t idx = ((size_t)(b * 64 + t) * 512 + e) * 32
                     + (((c0 >> 3) ^ ((e >> 1) & 3)) << 3) + (c0 & 7);
        *(short4v*)&Vtb[idx] = v;   // tile-contiguous V, read-swizzle pre-baked
      }
    }
  } else {
    short* dst = (g == 0 ? Qb : Kb);
    float sc = (g == 0 ? SCALE * LOG2E : 1.0f);  // Q pre-scaled, exp2 domain
    #pragma unroll
    for (int mi = 0; mi < 4; mi++) {
      int gm0 = m0 + mi * 16 + lg * 4;
      #pragma unroll
      for (int ni = 0; ni < 4; ni++) {
        int gn = wid * 64 + ni * 16 + l15;
        #pragma unroll
        for (int r = 0; r < 4; r++)
          dst[(size_t)(gm0 + r) * DIM + gn] = f2bs(acc[mi][ni][r] * sc);
      }
    }
  }
}

// ---- flash attention (causal) — R15 structure, frozen ----------------------
__device__ __forceinline__ void stage_k(const short* __restrict__ Kb,
                                        short* Klbuf,
                                        int batch, int t, int wid, int lane) {
  #pragma unroll
  for (int ii = 0; ii < 4; ii++) {          // K: rows wid, wid+8, wid+16, wid+24
    int r = wid + ii * 8;                   // r&7 == wid
    const short* src = Kb + (size_t)(batch * LSEQ + t * 32 + r) * DIM + ((lane ^ wid) * 8);
    gld16(src, Klbuf + r * 512);
  }
}
__device__ __forceinline__ void stage_v(const short* __restrict__ Vtb,
                                        short* Vlbuf,
                                        int batch, int t, int wid, int lane) {
  const short* vt = Vtb + (size_t)(batch * 64 + t) * 16384;  // contiguous 32KB
  #pragma unroll
  for (int ii = 0; ii < 4; ii++) {
    int s = wid * 4 + ii;
    gld16(vt + s * 512 + lane * 8, Vlbuf + s * 512);
  }
}

__global__ __launch_bounds__(512, 2) void attn_kernel(
    const short* __restrict__ Qb, const short* __restrict__ Kb,
    const short* __restrict__ Vtb, float* __restrict__ out) {
  __shared__ short Kl[2][32 * 512];   // 64 KB dbuf
  __shared__ short Vl[2][512 * 32];   // 64 KB dbuf
  __shared__ short P_lds[8][16][40];  // per-wave P transpose; 16B-aligned rows
  int tid = threadIdx.x, lane = tid & 63, wid = tid >> 6;
  int l15 = lane & 15, lg = lane >> 4;
  int batch = blockIdx.x;
  f32x4 zero4 = {0.f, 0.f, 0.f, 0.f};
  short8 ones;
  #pragma unroll
  for (int i = 0; i < 8; i++) ones[i] = (short)0x3F80;

  // lane-const LDS offsets (shorts):
  int a0 = (l15 >> 2) & 1, b0 = l15 & 3;
  int kqE = l15 * 512 + 8 * (lg ^ b0) + 32 * a0;  // even-kt base (+8192 for c=1)
  int kqO = l15 * 512 + 8 * (lg ^ b0) - 32 * a0;  // odd-kt base
  int voff = l15 * 32 + 8 * (lg ^ ((l15 >> 1) & 3));  // V base (+512*et)
  short* pw = &P_lds[wid][lg * 4][l15];               // P write (+40*r, +16*c)
  const short* pr = &P_lds[wid][l15][lg * 8];         // P read (A-frag, aligned)

  for (int qpass = 0; qpass < 2; qpass++) {
    int qt = qpass ? (int)blockIdx.y : 15 - (int)blockIdx.y;  // long pass first
    int qb0 = qt * 128;
    int q0w = qb0 + wid * 16;
    int nt = qt * 4 + 4;

    stage_k(Kb, Kl[0], batch, 0, wid, lane);  // prologue: K(0) only

    const short* qrow = Qb + (size_t)(batch * LSEQ + q0w + l15) * DIM;
    short8 qf[16];  // Q rows in regs (SCALE*LOG2E pre-folded)
    #pragma unroll
    for (int kt = 0; kt < 16; kt++) qf[kt] = *(const short8*)(qrow + kt * 32 + lg * 8);

    f32x4 oacc[32];
    #pragma unroll
    for (int i = 0; i < 32; i++) oacc[i] = zero4;
    f32x4 dacc = zero4;   // per-row softmax denominator (via ones-MFMA)
    float mrun = -1e30f;  // wave-uniform running max (exp2 domain)
    short8 pa;            // P fragment of tile t-1 (valid when act(t-1))

    __syncthreads();  // drains prologue stage (vmcnt) + syncs

    for (int t = 0; t < nt; t++) {
      int cur = t & 1;
      if (t + 1 < nt)
        stage_k(Kb, Kl[cur ^ 1], batch, t + 1, wid, lane);
      stage_v(Vtb, Vl[cur], batch, t, wid, lane);  // V(t): consumed iter t+1

      bool act = (t * 32 <= q0w + 15);
      bool actp = (t > 0) && ((t - 1) * 32 <= q0w + 15);
      f32x4 sacc[2] = {zero4, zero4};
      if (act && actp) {
        // merged block: QK(t) interleaved with PV(t-1) (independent streams)
        const short* pE = Kl[cur] + kqE;
        const short* pO = Kl[cur] + kqO;
        const short* vb = Vl[cur ^ 1] + voff;
        __builtin_amdgcn_s_setprio(1);
        dacc = __builtin_amdgcn_mfma_f32_16x16x32_bf16(pa, ones, dacc, 0, 0, 0);
        #pragma unroll
        for (int kt = 0; kt < 16; kt += 2) {
          short8 k0 = *(const short8*)(pE + 32 * kt);
          short8 k1 = *(const short8*)(pE + 8192 + 32 * kt);
          sacc[0] = __builtin_amdgcn_mfma_f32_16x16x32_bf16(qf[kt], k0, sacc[0], 0, 0, 0);
          sacc[1] = __builtin_amdgcn_mfma_f32_16x16x32_bf16(qf[kt], k1, sacc[1], 0, 0, 0);
          short8 v0 = *(const short8*)(vb + (kt * 2) * 512);
          short8 v1 = *(const short8*)(vb + (kt * 2 + 1) * 512);
          oacc[kt * 2] = __builtin_amdgcn_mfma_f32_16x16x32_bf16(pa, v0, oacc[kt * 2], 0, 0, 0);
          oacc[kt * 2 + 1] = __builtin_amdgcn_mfma_f32_16x16x32_bf16(pa, v1, oacc[kt * 2 + 1], 0, 0, 0);
          short8 k2 = *(const short8*)(pO + 32 * (kt + 1));
          short8 k3 = *(const short8*)(pO + 8192 + 32 * (kt + 1));
          sacc[0] = __builtin_amdgcn_mfma_f32_16x16x32_bf16(qf[kt + 1], k2, sacc[0], 0, 0, 0);
          sacc[1] = __builtin_amdgcn_mfma_f32_16x16x32_bf16(qf[kt + 1], k3, sacc[1], 0, 0, 0);
          short8 v2 = *(const short8*)(vb + (kt * 2 + 2) * 512);
          short8 v3 = *(const short8*)(vb + (kt * 2 + 3) * 512);
          oacc[kt * 2 + 2] = __builtin_amdgcn_mfma_f32_16x16x32_bf16(pa, v2, oacc[kt * 2 + 2], 0, 0, 0);
          oacc[kt * 2 + 3] = __builtin_amdgcn_mfma_f32_16x16x32_bf16(pa, v3, oacc[kt * 2 + 3], 0, 0, 0);
        }
        __builtin_amdgcn_s_setprio(0);
      } else if (act) {  // t == 0: QK only
        const short* pE = Kl[cur] + kqE;
        const short* pO = Kl[cur] + kqO;
        __builtin_amdgcn_s_setprio(1);
        #pragma unroll
        for (int kt = 0; kt < 16; kt += 2) {
          short8 k0 = *(const short8*)(pE + 32 * kt);
          short8 k1 = *(const short8*)(pE + 8192 + 32 * kt);
          sacc[0] = __builtin_amdgcn_mfma_f32_16x16x32_bf16(qf[kt], k0, sacc[0], 0, 0, 0);
          sacc[1] = __builtin_amdgcn_mfma_f32_16x16x32_bf16(qf[kt], k1, sacc[1], 0, 0, 0);
          short8 k2 = *(const short8*)(pO + 32 * (kt + 1));
          short8 k3 = *(const short8*)(pO + 8192 + 32 * (kt + 1));
          sacc[0] = __builtin_amdgcn_mfma_f32_16x16x32_bf16(qf[kt + 1], k2, sacc[0], 0, 0, 0);
          sacc[1] = __builtin_amdgcn_mfma_f32_16x16x32_bf16(qf[kt + 1], k3, sacc[1], 0, 0, 0);
        }
        __builtin_amdgcn_s_setprio(0);
      } else if (actp) {  // transition tile: PV(t-1) only
        const short* vb = Vl[cur ^ 1] + voff;
        __builtin_amdgcn_s_setprio(1);
        dacc = __builtin_amdgcn_mfma_f32_16x16x32_bf16(pa, ones, dacc, 0, 0, 0);
        #pragma unroll
        for (int et = 0; et < 32; et++) {
          short8 bv = *(const short8*)(vb + et * 512);
          oacc[et] = __builtin_amdgcn_mfma_f32_16x16x32_bf16(pa, bv, oacc[et], 0, 0, 0);
        }
        __builtin_amdgcn_s_setprio(0);
      }
      if (act) {  // softmax(t) -> P_lds -> pa (regs) for next iter's PV
        if (t * 32 + 31 > q0w) {  // diagonal tiles only: causal mask
          #pragma unroll
          for (int r = 0; r < 4; r++) {
            int q = q0w + lg * 4 + r;
            if (t * 32 + l15 > q) sacc[0][r] = -1e30f;
            if (t * 32 + 16 + l15 > q) sacc[1][r] = -1e30f;
          }
        }
        float lm = fmaxf(
            fmaxf(fmaxf(sacc[0][0], sacc[0][1]), fmaxf(sacc[0][2], sacc[0][3])),
            fmaxf(fmaxf(sacc[1][0], sacc[1][1]), fmaxf(sacc[1][2], sacc[1][3])));
        if (__any(lm > mrun + 11.5f)) {  // rare: raise the wave max
          float mx = lm;
          #pragma unroll
          for (int off = 1; off < 64; off <<= 1) mx = fmaxf(mx, __shfl_xor(mx, off, 64));
          float alpha = exp2f(mrun - mx);
          mrun = mx;
          dacc[0] *= alpha; dacc[1] *= alpha; dacc[2] *= alpha; dacc[3] *= alpha;
          #pragma unroll
          for (int et = 0; et < 32; et++) {
            oacc[et][0] *= alpha; oacc[et][1] *= alpha;
            oacc[et][2] *= alpha; oacc[et][3] *= alpha;
          }
        }
        #pragma unroll
        for (int r = 0; r < 4; r++) {
          pw[r * 40] = f2bs(exp2f(sacc[0][r] - mrun));
          pw[r * 40 + 16] = f2bs(exp2f(sacc[1][r] - mrun));
        }
        pa = *(const short8*)pr;  // wave-local RAW
      }
      __syncthreads();  // drains prefetch (vmcnt) + releases buffers
    }
    // drain: PV(nt-1) for waves active at the last tile
    if ((nt - 1) * 32 <= q0w + 15) {
      const short* vb = Vl[(nt - 1) & 1] + voff;
      dacc = __builtin_amdgcn_mfma_f32_16x16x32_bf16(pa, ones, dacc, 0, 0, 0);
      #pragma unroll
      for (int et = 0; et < 32; et++) {
        short8 bv = *(const short8*)(vb + et * 512);
        oacc[et] = __builtin_amdgcn_mfma_f32_16x16x32_bf16(pa, bv, oacc[et], 0, 0, 0);
      }
    }
    // epilogue: per-wave divide by denominator, write 16 q-rows x 512 dims
    float inv[4];
    #pragma unroll
    for (int r = 0; r < 4; r++) inv[r] = 1.0f / dacc[r];
    #pragma unroll
    for (int et = 0; et < 32; et++)
      #pragma unroll
      for (int r = 0; r < 4; r++) {
        int q = q0w + lg * 4 + r;
        out[((size_t)(batch * LSEQ + q)) * DIM + et * 16 + l15] = oacc[et][r] * inv[r];
      }
    __syncthreads();  // LDS reuse safe before next qpass
  }
}

extern "C" void kernel_launch(void* const* d_in, const int* in_sizes, int n_in,
                              void* d_out, int out_size, void* d_ws, size_t ws_size,
                              hipStream_t stream) {
  const float* Ez = (const float*)d_in[0];
  const float* Wq = (const float*)d_in[1];
  const float* Wk = (const float*)d_in[2];
  const float* Wv = (const float*)d_in[3];
  const int* zp = (const int*)d_in[4];
  float* out = (float*)d_out;
  short* Qb = (short*)d_ws;
  short* Kb = Qb + (size_t)NB * LSEQ * DIM;
  short* Vtb = Kb + (size_t)NB * LSEQ * DIM;
  short* Wb = (short*)d_out;                 // scratch (proj done before attn writes)
  short* Ezb = Wb + (size_t)3 * 16 * 512 * 32;  // 67 MB, fits in d_out (134 MB)
  // wcvt: 98304 W-threads + 4194304 Ez-threads = 4292608 -> 16768 blocks x 256
  hipLaunchKernelGGL(wcvt_kernel, dim3(16768), dim3(256), 0, stream,
                     Wq, Wk, Wv, zp, Ez, Wb, Ezb);
  hipLaunchKernelGGL(proj_kernel, dim3(1024, 1, 3), dim3(512), 0, stream,
                     Ezb, Wb, Qb, Kb, Vtb);
  hipLaunchKernelGGL(attn_kernel, dim3(32, 8), dim3(512), 0, stream,
                     Qb, Kb, Vtb, out);
}

// Round 20
// 403.141 us; speedup vs baseline: 1.2787x; 1.0046x over previous
//
#include <hip/hip_runtime.h>
#include <hip/hip_bf16.h>

// SelfAttention: out = softmax(causal((Ez Wq^T)(Ez Wk^T)^T / sqrt(512))) (Ez Wv^T)
// B=32, L=2048, DIM=512. f32 in/out; bf16 MFMA internally.
// ws: Qb (bf16, Q*SCALE*LOG2E), Kb (bf16), Vtb (bf16, [b][t][e][32] tile-contig,
// chunk-XOR pre-baked). d_out scratch: Wb (bf16 [g][kt][n][32] swizzled) +
// Ezb (bf16 [mt][kt][64][32], A-swizzle baked).
// R20 = R19 + proj tile BM=128 x BN=256 (square 64x64 wave tiles, 2m x 4n):
// staging/output -33%, W panel per block halved; occupancy unchanged (48KB).

typedef __attribute__((ext_vector_type(8))) short short8;
typedef __attribute__((ext_vector_type(4))) short short4v;
typedef __attribute__((ext_vector_type(4))) float f32x4;

#define DIM 512
#define LSEQ 2048
#define NB 32
#define SCALE 0.04419417382415922f
#define LOG2E 1.4426950408889634f

__device__ __forceinline__ short f2bs(float f) {
  __hip_bfloat16 h = __float2bfloat16(f);
  return __builtin_bit_cast(short, h);
}

__device__ __forceinline__ void gld16(const void* g, void* l) {
  __builtin_amdgcn_global_load_lds(
      (const unsigned int __attribute__((address_space(1)))*)g,
      (unsigned int __attribute__((address_space(3)))*)l, 16, 0, 0);
}

// ---- convert W[z] AND Ez to bf16 (swizzles pre-baked) ----------------------
__global__ __launch_bounds__(256) void wcvt_kernel(
    const float* __restrict__ Wq, const float* __restrict__ Wk,
    const float* __restrict__ Wv, const int* __restrict__ zp,
    const float* __restrict__ Ez,
    short* __restrict__ Wb, short* __restrict__ Ezb) {
  int z = *zp;
  int i = blockIdx.x * 256 + threadIdx.x;
  if (i < 98304) {  // W: 3 x 512x512 / 8
    int g = i >> 15;
    int off = (i & 32767) * 8;                 // flat [n][d], d fast
    int n = off >> 9, d0 = off & 511;
    int kt = d0 >> 5, c = d0 & 31;
    int sw = ((c >> 3) ^ ((n >> 1) & 3));
    const float* src = (g == 0 ? Wq : (g == 1 ? Wk : Wv)) + (size_t)z * DIM * DIM + off;
    float4 a = *(const float4*)src, b = *(const float4*)(src + 4);
    short8 v;
    v[0]=f2bs(a.x); v[1]=f2bs(a.y); v[2]=f2bs(a.z); v[3]=f2bs(a.w);
    v[4]=f2bs(b.x); v[5]=f2bs(b.y); v[6]=f2bs(b.z); v[7]=f2bs(b.w);
    *(short8*)&Wb[((size_t)(g * 16 + kt) * 512 + n) * 32 + sw * 8] = v;
  } else {  // Ez: 32*2048*512 / 8 elems
    size_t j = (size_t)(i - 98304);
    size_t off = j * 8;                        // flat [m][d], d fast
    int m = (int)(off >> 9), d0 = (int)(off & 511);
    int kt = d0 >> 5, c = d0 & 31;
    int mt = m >> 6, mr = m & 63;
    const float* src = Ez + off;
    float4 a = *(const float4*)src, b = *(const float4*)(src + 4);
    short8 v;
    v[0]=f2bs(a.x); v[1]=f2bs(a.y); v[2]=f2bs(a.z); v[3]=f2bs(a.w);
    v[4]=f2bs(b.x); v[5]=f2bs(b.y); v[6]=f2bs(b.z); v[7]=f2bs(b.w);
    size_t idx = (((size_t)mt * 16 + kt) * 64 + mr) * 32
                 + (((c >> 3) ^ ((mr >> 1) & 3)) << 3);  // A-swizzle baked (c&7==0)
    *(short8*)&Ezb[idx] = v;
  }
}

// ---- projection GEMM: C[m][n] = sum_d Ez[m][d] * W[n][d] -------------------
// BM=128, BN=256, BK=32; 8 waves as 2m x 4n grid of 64x64 tiles. A via gld16
// from Ezb, B via gld16 from Wb. 48KB LDS -> 2 blocks/CU.
__global__ __launch_bounds__(512, 4) void proj_kernel(
    const short* __restrict__ Ezb, const short* __restrict__ Wb,
    short* __restrict__ Qb, short* __restrict__ Kb, short* __restrict__ Vtb) {
  int g = blockIdx.z;
  int nh = blockIdx.y;
  const short* W = Wb + (size_t)g * 16 * 512 * 32 + nh * 8192;  // n-half base
  const short* EA = Ezb + (size_t)(2 * blockIdx.x) * 16 * 2048; // two mt slabs
  __shared__ short As[2][128 * 32];   // 16 KB dbuf
  __shared__ short Bs[2][256 * 32];   // 32 KB dbuf
  int tid = threadIdx.x, lane = tid & 63, wid = tid >> 6;
  int l15 = lane & 15, lg = lane >> 4;
  int m0 = blockIdx.x * 128;
  int wr = wid >> 2, wc = wid & 3;   // wave tile: m [wr*64,+64), n [wc*64,+64)
  int sw = (l15 >> 1) & 3;
  f32x4 zero4 = {0.f, 0.f, 0.f, 0.f};
  f32x4 acc[4][4];
  #pragma unroll
  for (int mi = 0; mi < 4; mi++)
    #pragma unroll
    for (int ni = 0; ni < 4; ni++) acc[mi][ni] = zero4;

  // A slab for this wave: wid<4 -> mt0 rows wid*16; wid>=4 -> mt1 rows (wid-4)*16
  const short* asrc = EA + (size_t)(wid >> 2) * 16 * 2048 + (wid & 3) * 512 + lane * 8;

  {  // prologue: stage A(0) + B(0)
    gld16(asrc, &As[0][wid * 512]);
    #pragma unroll
    for (int ii = 0; ii < 2; ii++) {
      int s = wid * 2 + ii;
      gld16(W + s * 512 + lane * 8, &Bs[0][s * 512]);
    }
  }
  __syncthreads();

  #pragma unroll 2
  for (int kt = 0; kt < 16; kt++) {
    int cur = kt & 1;
    if (kt < 15) {
      gld16(asrc + (size_t)(kt + 1) * 2048, &As[cur ^ 1][wid * 512]);
      #pragma unroll
      for (int ii = 0; ii < 2; ii++) {
        int s = wid * 2 + ii;
        gld16(W + (size_t)(kt + 1) * 16384 + s * 512 + lane * 8, &Bs[cur ^ 1][s * 512]);
      }
    }
    short8 af[4], bf[4];
    #pragma unroll
    for (int mi = 0; mi < 4; mi++)
      af[mi] = *(const short8*)&As[cur][(wr * 64 + mi * 16 + l15) * 32 + ((lg ^ sw) << 3)];
    #pragma unroll
    for (int ni = 0; ni < 4; ni++)
      bf[ni] = *(const short8*)&Bs[cur][(wc * 64 + ni * 16 + l15) * 32 + ((lg ^ sw) << 3)];
    __builtin_amdgcn_s_setprio(1);
    #pragma unroll
    for (int mi = 0; mi < 4; mi++)
      #pragma unroll
      for (int ni = 0; ni < 4; ni++)
        acc[mi][ni] = __builtin_amdgcn_mfma_f32_16x16x32_bf16(af[mi], bf[ni], acc[mi][ni], 0, 0, 0);
    __builtin_amdgcn_s_setprio(0);
    __syncthreads();  // drains gld16 prefetch (vmcnt), releases buffers
  }

  if (g == 2) {
    #pragma unroll
    for (int mi = 0; mi < 4; mi++) {
      int gm0 = m0 + wr * 64 + mi * 16 + lg * 4;
      int b = gm0 >> 11, l0 = gm0 & (LSEQ - 1);
      int t = l0 >> 5, c0 = l0 & 31;
      #pragma unroll
      for (int ni = 0; ni < 4; ni++) {
        int e = nh * 256 + wc * 64 + ni * 16 + l15;
        short4v v;
        v[0]=f2bs(acc[mi][ni][0]); v[1]=f2bs(acc[mi][ni][1]);
        v[2]=f2bs(acc[mi][ni][2]); v[3]=f2bs(acc[mi][ni][3]);
        size_t idx = ((size_t)(b * 64 + t) * 512 + e) * 32
                     + (((c0 >> 3) ^ ((e >> 1) & 3)) << 3) + (c0 & 7);
        *(short4v*)&Vtb[idx] = v;   // tile-contiguous V, read-swizzle pre-baked
      }
    }
  } else {
    short* dst = (g == 0 ? Qb : Kb);
    float sc = (g == 0 ? SCALE * LOG2E : 1.0f);  // Q pre-scaled, exp2 domain
    #pragma unroll
    for (int mi = 0; mi < 4; mi++) {
      int gm0 = m0 + wr * 64 + mi * 16 + lg * 4;
      #pragma unroll
      for (int ni = 0; ni < 4; ni++) {
        int gn = nh * 256 + wc * 64 + ni * 16 + l15;
        #pragma unroll
        for (int r = 0; r < 4; r++)
          dst[(size_t)(gm0 + r) * DIM + gn] = f2bs(acc[mi][ni][r] * sc);
      }
    }
  }
}

// ---- flash attention (causal) — R15 structure, frozen ----------------------
__device__ __forceinline__ void stage_k(const short* __restrict__ Kb,
                                        short* Klbuf,
                                        int batch, int t, int wid, int lane) {
  #pragma unroll
  for (int ii = 0; ii < 4; ii++) {          // K: rows wid, wid+8, wid+16, wid+24
    int r = wid + ii * 8;                   // r&7 == wid
    const short* src = Kb + (size_t)(batch * LSEQ + t * 32 + r) * DIM + ((lane ^ wid) * 8);
    gld16(src, Klbuf + r * 512);
  }
}
__device__ __forceinline__ void stage_v(const short* __restrict__ Vtb,
                                        short* Vlbuf,
                                        int batch, int t, int wid, int lane) {
  const short* vt = Vtb + (size_t)(batch * 64 + t) * 16384;  // contiguous 32KB
  #pragma unroll
  for (int ii = 0; ii < 4; ii++) {
    int s = wid * 4 + ii;
    gld16(vt + s * 512 + lane * 8, Vlbuf + s * 512);
  }
}

__global__ __launch_bounds__(512, 2) void attn_kernel(
    const short* __restrict__ Qb, const short* __restrict__ Kb,
    const short* __restrict__ Vtb, float* __restrict__ out) {
  __shared__ short Kl[2][32 * 512];   // 64 KB dbuf
  __shared__ short Vl[2][512 * 32];   // 64 KB dbuf
  __shared__ short P_lds[8][16][40];  // per-wave P transpose; 16B-aligned rows
  int tid = threadIdx.x, lane = tid & 63, wid = tid >> 6;
  int l15 = lane & 15, lg = lane >> 4;
  int batch = blockIdx.x;
  f32x4 zero4 = {0.f, 0.f, 0.f, 0.f};
  short8 ones;
  #pragma unroll
  for (int i = 0; i < 8; i++) ones[i] = (short)0x3F80;

  // lane-const LDS offsets (shorts):
  int a0 = (l15 >> 2) & 1, b0 = l15 & 3;
  int kqE = l15 * 512 + 8 * (lg ^ b0) + 32 * a0;  // even-kt base (+8192 for c=1)
  int kqO = l15 * 512 + 8 * (lg ^ b0) - 32 * a0;  // odd-kt base
  int voff = l15 * 32 + 8 * (lg ^ ((l15 >> 1) & 3));  // V base (+512*et)
  short* pw = &P_lds[wid][lg * 4][l15];               // P write (+40*r, +16*c)
  const short* pr = &P_lds[wid][l15][lg * 8];         // P read (A-frag, aligned)

  for (int qpass = 0; qpass < 2; qpass++) {
    int qt = qpass ? (int)blockIdx.y : 15 - (int)blockIdx.y;  // long pass first
    int qb0 = qt * 128;
    int q0w = qb0 + wid * 16;
    int nt = qt * 4 + 4;

    stage_k(Kb, Kl[0], batch, 0, wid, lane);  // prologue: K(0) only

    const short* qrow = Qb + (size_t)(batch * LSEQ + q0w + l15) * DIM;
    short8 qf[16];  // Q rows in regs (SCALE*LOG2E pre-folded)
    #pragma unroll
    for (int kt = 0; kt < 16; kt++) qf[kt] = *(const short8*)(qrow + kt * 32 + lg * 8);

    f32x4 oacc[32];
    #pragma unroll
    for (int i = 0; i < 32; i++) oacc[i] = zero4;
    f32x4 dacc = zero4;   // per-row softmax denominator (via ones-MFMA)
    float mrun = -1e30f;  // wave-uniform running max (exp2 domain)
    short8 pa;            // P fragment of tile t-1 (valid when act(t-1))

    __syncthreads();  // drains prologue stage (vmcnt) + syncs

    for (int t = 0; t < nt; t++) {
      int cur = t & 1;
      if (t + 1 < nt)
        stage_k(Kb, Kl[cur ^ 1], batch, t + 1, wid, lane);
      stage_v(Vtb, Vl[cur], batch, t, wid, lane);  // V(t): consumed iter t+1

      bool act = (t * 32 <= q0w + 15);
      bool actp = (t > 0) && ((t - 1) * 32 <= q0w + 15);
      f32x4 sacc[2] = {zero4, zero4};
      if (act && actp) {
        // merged block: QK(t) interleaved with PV(t-1) (independent streams)
        const short* pE = Kl[cur] + kqE;
        const short* pO = Kl[cur] + kqO;
        const short* vb = Vl[cur ^ 1] + voff;
        __builtin_amdgcn_s_setprio(1);
        dacc = __builtin_amdgcn_mfma_f32_16x16x32_bf16(pa, ones, dacc, 0, 0, 0);
        #pragma unroll
        for (int kt = 0; kt < 16; kt += 2) {
          short8 k0 = *(const short8*)(pE + 32 * kt);
          short8 k1 = *(const short8*)(pE + 8192 + 32 * kt);
          sacc[0] = __builtin_amdgcn_mfma_f32_16x16x32_bf16(qf[kt], k0, sacc[0], 0, 0, 0);
          sacc[1] = __builtin_amdgcn_mfma_f32_16x16x32_bf16(qf[kt], k1, sacc[1], 0, 0, 0);
          short8 v0 = *(const short8*)(vb + (kt * 2) * 512);
          short8 v1 = *(const short8*)(vb + (kt * 2 + 1) * 512);
          oacc[kt * 2] = __builtin_amdgcn_mfma_f32_16x16x32_bf16(pa, v0, oacc[kt * 2], 0, 0, 0);
          oacc[kt * 2 + 1] = __builtin_amdgcn_mfma_f32_16x16x32_bf16(pa, v1, oacc[kt * 2 + 1], 0, 0, 0);
          short8 k2 = *(const short8*)(pO + 32 * (kt + 1));
          short8 k3 = *(const short8*)(pO + 8192 + 32 * (kt + 1));
          sacc[0] = __builtin_amdgcn_mfma_f32_16x16x32_bf16(qf[kt + 1], k2, sacc[0], 0, 0, 0);
          sacc[1] = __builtin_amdgcn_mfma_f32_16x16x32_bf16(qf[kt + 1], k3, sacc[1], 0, 0, 0);
          short8 v2 = *(const short8*)(vb + (kt * 2 + 2) * 512);
          short8 v3 = *(const short8*)(vb + (kt * 2 + 3) * 512);
          oacc[kt * 2 + 2] = __builtin_amdgcn_mfma_f32_16x16x32_bf16(pa, v2, oacc[kt * 2 + 2], 0, 0, 0);
          oacc[kt * 2 + 3] = __builtin_amdgcn_mfma_f32_16x16x32_bf16(pa, v3, oacc[kt * 2 + 3], 0, 0, 0);
        }
        __builtin_amdgcn_s_setprio(0);
      } else if (act) {  // t == 0: QK only
        const short* pE = Kl[cur] + kqE;
        const short* pO = Kl[cur] + kqO;
        __builtin_amdgcn_s_setprio(1);
        #pragma unroll
        for (int kt = 0; kt < 16; kt += 2) {
          short8 k0 = *(const short8*)(pE + 32 * kt);
          short8 k1 = *(const short8*)(pE + 8192 + 32 * kt);
          sacc[0] = __builtin_amdgcn_mfma_f32_16x16x32_bf16(qf[kt], k0, sacc[0], 0, 0, 0);
          sacc[1] = __builtin_amdgcn_mfma_f32_16x16x32_bf16(qf[kt], k1, sacc[1], 0, 0, 0);
          short8 k2 = *(const short8*)(pO + 32 * (kt + 1));
          short8 k3 = *(const short8*)(pO + 8192 + 32 * (kt + 1));
          sacc[0] = __builtin_amdgcn_mfma_f32_16x16x32_bf16(qf[kt + 1], k2, sacc[0], 0, 0, 0);
          sacc[1] = __builtin_amdgcn_mfma_f32_16x16x32_bf16(qf[kt + 1], k3, sacc[1], 0, 0, 0);
        }
        __builtin_amdgcn_s_setprio(0);
      } else if (actp) {  // transition tile: PV(t-1) only
        const short* vb = Vl[cur ^ 1] + voff;
        __builtin_amdgcn_s_setprio(1);
        dacc = __builtin_amdgcn_mfma_f32_16x16x32_bf16(pa, ones, dacc, 0, 0, 0);
        #pragma unroll
        for (int et = 0; et < 32; et++) {
          short8 bv = *(const short8*)(vb + et * 512);
          oacc[et] = __builtin_amdgcn_mfma_f32_16x16x32_bf16(pa, bv, oacc[et], 0, 0, 0);
        }
        __builtin_amdgcn_s_setprio(0);
      }
      if (act) {  // softmax(t) -> P_lds -> pa (regs) for next iter's PV
        if (t * 32 + 31 > q0w) {  // diagonal tiles only: causal mask
          #pragma unroll
          for (int r = 0; r < 4; r++) {
            int q = q0w + lg * 4 + r;
            if (t * 32 + l15 > q) sacc[0][r] = -1e30f;
            if (t * 32 + 16 + l15 > q) sacc[1][r] = -1e30f;
          }
        }
        float lm = fmaxf(
            fmaxf(fmaxf(sacc[0][0], sacc[0][1]), fmaxf(sacc[0][2], sacc[0][3])),
            fmaxf(fmaxf(sacc[1][0], sacc[1][1]), fmaxf(sacc[1][2], sacc[1][3])));
        if (__any(lm > mrun + 11.5f)) {  // rare: raise the wave max
          float mx = lm;
          #pragma unroll
          for (int off = 1; off < 64; off <<= 1) mx = fmaxf(mx, __shfl_xor(mx, off, 64));
          float alpha = exp2f(mrun - mx);
          mrun = mx;
          dacc[0] *= alpha; dacc[1] *= alpha; dacc[2] *= alpha; dacc[3] *= alpha;
          #pragma unroll
          for (int et = 0; et < 32; et++) {
            oacc[et][0] *= alpha; oacc[et][1] *= alpha;
            oacc[et][2] *= alpha; oacc[et][3] *= alpha;
          }
        }
        #pragma unroll
        for (int r = 0; r < 4; r++) {
          pw[r * 40] = f2bs(exp2f(sacc[0][r] - mrun));
          pw[r * 40 + 16] = f2bs(exp2f(sacc[1][r] - mrun));
        }
        pa = *(const short8*)pr;  // wave-local RAW
      }
      __syncthreads();  // drains prefetch (vmcnt) + releases buffers
    }
    // drain: PV(nt-1) for waves active at the last tile
    if ((nt - 1) * 32 <= q0w + 15) {
      const short* vb = Vl[(nt - 1) & 1] + voff;
      dacc = __builtin_amdgcn_mfma_f32_16x16x32_bf16(pa, ones, dacc, 0, 0, 0);
      #pragma unroll
      for (int et = 0; et < 32; et++) {
        short8 bv = *(const short8*)(vb + et * 512);
        oacc[et] = __builtin_amdgcn_mfma_f32_16x16x32_bf16(pa, bv, oacc[et], 0, 0, 0);
      }
    }
    // epilogue: per-wave divide by denominator, write 16 q-rows x 512 dims
    float inv[4];
    #pragma unroll
    for (int r = 0; r < 4; r++) inv[r] = 1.0f / dacc[r];
    #pragma unroll
    for (int et = 0; et < 32; et++)
      #pragma unroll
      for (int r = 0; r < 4; r++) {
        int q = q0w + lg * 4 + r;
        out[((size_t)(batch * LSEQ + q)) * DIM + et * 16 + l15] = oacc[et][r] * inv[r];
      }
    __syncthreads();  // LDS reuse safe before next qpass
  }
}

extern "C" void kernel_launch(void* const* d_in, const int* in_sizes, int n_in,
                              void* d_out, int out_size, void* d_ws, size_t ws_size,
                              hipStream_t stream) {
  const float* Ez = (const float*)d_in[0];
  const float* Wq = (const float*)d_in[1];
  const float* Wk = (const float*)d_in[2];
  const float* Wv = (const float*)d_in[3];
  const int* zp = (const int*)d_in[4];
  float* out = (float*)d_out;
  short* Qb = (short*)d_ws;
  short* Kb = Qb + (size_t)NB * LSEQ * DIM;
  short* Vtb = Kb + (size_t)NB * LSEQ * DIM;
  short* Wb = (short*)d_out;                 // scratch (proj done before attn writes)
  short* Ezb = Wb + (size_t)3 * 16 * 512 * 32;  // 67 MB, fits in d_out (134 MB)
  hipLaunchKernelGGL(wcvt_kernel, dim3(16768), dim3(256), 0, stream,
                     Wq, Wk, Wv, zp, Ez, Wb, Ezb);
  hipLaunchKernelGGL(proj_kernel, dim3(512, 2, 3), dim3(512), 0, stream,
                     Ezb, Wb, Qb, Kb, Vtb);
  hipLaunchKernelGGL(attn_kernel, dim3(32, 8), dim3(512), 0, stream,
                     Qb, Kb, Vtb, out);
}